// Round 5
// baseline (370.221 us; speedup 1.0000x reference)
//
#include <hip/hip_runtime.h>
#include <stdint.h>

#define Bq   4
#define Nseq 2048
#define NH   16
#define HD   64
#define DIMD 1024

typedef float  f32x4   __attribute__((ext_vector_type(4)));
typedef float  f32x16  __attribute__((ext_vector_type(16)));
typedef __bf16 bf16x8  __attribute__((ext_vector_type(8)));
typedef short  s16x4   __attribute__((ext_vector_type(4)));

typedef __attribute__((address_space(1))) void as1_void;
typedef __attribute__((address_space(3))) void as3_void;

static __device__ __forceinline__ uint16_t f2bf(float f) {
    uint32_t u = __builtin_bit_cast(uint32_t, f);
    u += 0x7fffu + ((u >> 16) & 1u);          // RNE
    return (uint16_t)(u >> 16);
}

// truncation-pack two fp32 -> packed bf16x2 (p>=0, 1-ulp bias, cancels in p/l)
static __device__ __forceinline__ uint32_t pk2(float a, float b) {
    uint32_t ua = __builtin_bit_cast(uint32_t, a);
    uint32_t ub = __builtin_bit_cast(uint32_t, b);
    return (ua >> 16) | (ub & 0xffff0000u);
}

static __device__ __forceinline__ void asyncLoad16(const uint16_t* g, uint16_t* l) {
    __builtin_amdgcn_global_load_lds((as1_void*)g, (as3_void*)l, 16, 0, 0);
}

static __device__ __forceinline__ void storeOut(float* p, float v)    { *p = v; }
static __device__ __forceinline__ void storeOut(uint16_t* p, float v) { *p = f2bf(v); }

// ---------------------------------------------------------------------------
// cast fp32 -> bf16 : x (8388608) then Wq,Wk,Wv,Wo (4 x 1048576), dst contiguous
// Wq is pre-scaled by SCALE*log2(e) so attention can use exp2 on raw QK dots.
// ---------------------------------------------------------------------------
__global__ void cast_all(const float* __restrict__ x,
                         const float* __restrict__ wq, const float* __restrict__ wk,
                         const float* __restrict__ wv, const float* __restrict__ wo,
                         uint16_t* __restrict__ dst) {
    size_t i = ((size_t)blockIdx.x * blockDim.x + threadIdx.x) * 4;  // elem idx
    const float* src; size_t off; float scale = 1.0f;
    if (i < 8388608) { src = x; off = i; }
    else {
        size_t wI = i - 8388608;
        size_t wi = wI >> 20;
        off = wI & 1048575;
        src = (wi == 0) ? wq : (wi == 1) ? wk : (wi == 2) ? wv : wo;
        if (wi == 0) scale = 0.18033688011112042f;   // (1/sqrt(64)) * log2(e)
    }
    float4 v = *(const float4*)(src + off);
    ushort4 o;
    o.x = f2bf(v.x * scale); o.y = f2bf(v.y * scale);
    o.z = f2bf(v.z * scale); o.w = f2bf(v.w * scale);
    *(ushort4*)(dst + i) = o;
}

// ---------------------------------------------------------------------------
// GEMM  C[m][n] = sum_k A[m][k] * W[n][k]   (B^T layout, both row-major over K)
// 128x128 tile, BK=64, 256 thr = 4 waves (2x2), wave = 64x64 via 2x2 tiles of
// 32x32x16 MFMA. (R0-proven structure: 68.5 us on the QKV shape; two phase-
// schedule rewrites both regressed -- see R1/R2 notes. Left untouched.)
// LDS rows = 8 chunks of 16B, pos = chunk ^ (m&7): conflict-free b128 reads.
// Grid (x = m-block, y = sec*8+n): XCD = linear%8 = m%8, pinning each x-panel
// to one XCD's L2 across all consumer blocks.
// Section vSec (V projection) writes TRANSPOSED per (b,h): vt[(b*16+h)*64+d][n].
// C/D layout (32x32): col = lane&31, row = (reg&3) + 8*(reg>>2) + 4*(lane>>5).
// ---------------------------------------------------------------------------
template <typename OutT>
__global__ __launch_bounds__(256) void gemm_bt(
    const uint16_t* __restrict__ A, const uint16_t* __restrict__ W0,
    OutT* __restrict__ C0, int K, int Nld, int blocksPerSec,
    size_t wSecStride, size_t cSecStride, uint16_t* __restrict__ vtb, int vSec)
{
    __shared__ __align__(16) uint16_t As[128*64];
    __shared__ __align__(16) uint16_t Bs[128*64];

    const int t = threadIdx.x, lane = t & 63, w = t >> 6;
    const int wr = w >> 1, wc = w & 1;
    const int half = lane >> 5, ml = lane & 31;

    const int m0  = blockIdx.x * 128;
    const int sec = blockIdx.y / blocksPerSec;
    const int n0  = (blockIdx.y % blocksPerSec) * 128;
    const uint16_t* Wp = W0 + (size_t)sec * wSecStride;
    OutT* C = C0 + (size_t)sec * cSecStride;

    // staging: slot s = t + 256*i -> row = s>>3, chunk pos = s&7,
    // global chunk g = (s&7) ^ (row&7)
    int srow[4], sg[4];
    #pragma unroll
    for (int i = 0; i < 4; ++i) {
        int s = t + 256*i;
        srow[i] = s >> 3;
        sg[i]   = (s & 7) ^ (srow[i] & 7);
    }

    // fragment rows: A row m (per 32-tile), B row n; lane holds k = half*8+j
    int arow[2], brow[2];
    #pragma unroll
    for (int i = 0; i < 2; ++i) {
        arow[i] = wr*64 + i*32 + ml;
        brow[i] = wc*64 + i*32 + ml;
    }

    f32x16 acc[2][2] = {};

    for (int k0 = 0; k0 < K; k0 += 64) {
        __syncthreads();
        #pragma unroll
        for (int i = 0; i < 4; ++i) {
            asyncLoad16(A  + (size_t)(m0 + srow[i])*K + k0 + sg[i]*8,
                        As + (size_t)(w*64 + 256*i)*8);
            asyncLoad16(Wp + (size_t)(n0 + srow[i])*K + k0 + sg[i]*8,
                        Bs + (size_t)(w*64 + 256*i)*8);
        }
        __syncthreads();

        #pragma unroll
        for (int s = 0; s < 4; ++s) {            // k-step of 16
            const int chunk = s*2 + half;
            bf16x8 af[2], bfr[2];
            #pragma unroll
            for (int i = 0; i < 2; ++i) {
                int m = arow[i];
                af[i]  = *(const bf16x8*)(As + (size_t)(m*8 + (chunk ^ (m & 7)))*8);
                int n = brow[i];
                bfr[i] = *(const bf16x8*)(Bs + (size_t)(n*8 + (chunk ^ (n & 7)))*8);
            }
            #pragma unroll
            for (int mt = 0; mt < 2; ++mt)
                #pragma unroll
                for (int nt = 0; nt < 2; ++nt)
                    acc[mt][nt] = __builtin_amdgcn_mfma_f32_32x32x16_bf16(
                        af[mt], bfr[nt], acc[mt][nt], 0, 0, 0);
        }
    }

    if (vtb != nullptr && sec == vSec) {
        // vt[(b*16+h)*64+d][token]; reg groups of 4 are consecutive tokens
        #pragma unroll
        for (int mt = 0; mt < 2; ++mt)
            #pragma unroll
            for (int nt = 0; nt < 2; ++nt) {
                int colg = n0 + wc*64 + nt*32 + ml;               // dim
                int hh = colg >> 6, dd = colg & 63;
                #pragma unroll
                for (int g = 0; g < 4; ++g) {
                    int rowg = m0 + wr*64 + mt*32 + 8*g + 4*half; // token (+reg&3)
                    int bb = rowg >> 11, nn = rowg & 2047;
                    ushort4 o4;
                    o4.x = f2bf(acc[mt][nt][4*g + 0]);
                    o4.y = f2bf(acc[mt][nt][4*g + 1]);
                    o4.z = f2bf(acc[mt][nt][4*g + 2]);
                    o4.w = f2bf(acc[mt][nt][4*g + 3]);
                    *(ushort4*)(vtb + ((size_t)((bb*NH + hh)*HD + dd))*Nseq + nn) = o4;
                }
            }
    } else {
        #pragma unroll
        for (int mt = 0; mt < 2; ++mt)
            #pragma unroll
            for (int nt = 0; nt < 2; ++nt) {
                int col = n0 + wc*64 + nt*32 + ml;
                #pragma unroll
                for (int r = 0; r < 16; ++r) {
                    int row = m0 + wr*64 + mt*32 + (r & 3) + 8*(r >> 2) + 4*half;
                    storeOut(&C[(size_t)row * Nld + col], acc[mt][nt][r]);
                }
            }
    }
}

// ---------------------------------------------------------------------------
// Flash attention, causal, no-max online softmax, S^T formulation -- NO LDS.
//   R5 change: all operands (Q, K, V^T fragments) load global -> register.
//   Rationale (R3 counters: MfmaUtil 15, VALU 32, HBM 4%, occupancy 26%,
//   conflicts 0; R4 counted-vmcnt gained only ~1us): attn is stalled on
//   cross-wave lockstep + load latency, NOT on any pipe. But K/V per (b,h)
//   is 512 KB and all 16 q-blocks of a bh are XCD-pinned (bh%8): per-XCD
//   working set ~4 MB = L2-resident; the 4 waves of a block read the SAME
//   8 KB tile -> L1 absorbs the intra-block re-reads. So LDS staging buys
//   nothing (guide lesson #7) and its barriers cost the lockstep.
//   Zero __shared__, zero barriers, zero staging instrs; per-wave exact
//   trip count end_w; waves fully independent; 12 waves/CU hide latency.
// Address math (derived from the verified LDS path: read pos = chunk^(row&7)
// of data staged at gg = (s&7)^(row&7)  ==>  plain global chunk):
//   qf[qt][ks] = Q[tokBase+q0+w*32+qt*16+c][hcol + (ks*4+quad)*8 ..+8]
//   kf(nt,ks)  = K[tokBase+k0+nt*16+c][hcol + (ks*4+quad)*8 ..+8]
//   vf(s4,dt)  = Vt[bh*64+dt*16+c][k0 + s4*16 + quad*4 ..+4]
// PV stays on mfma_16x16x16bf16_1k: A-frag k = quad*4+j matches vf tokens.
// Grid (64 bh, 16 tile-slots); qi = perm(y) balances per-CU k-iters; XCD =
// bh%8 so all q-tiles of one (b,h) share an XCD's L2.
// Q/K: [B*N,1024] bf16; Vt: [(b*16+h)*64+d][2048] bf16.
// ---------------------------------------------------------------------------
__global__ __launch_bounds__(256, 3) void attn(
    const uint16_t* __restrict__ Q, const uint16_t* __restrict__ K,
    const uint16_t* __restrict__ Vt, uint16_t* __restrict__ O)
{
    const int t = threadIdx.x, lane = t & 63, w = t >> 6;
    const int quad = lane >> 4, c = lane & 15;
    const int y = blockIdx.y;
    const int qi = (y < 4) ? (15 - y) : (y < 8) ? (y + 4) : (y < 12) ? (y - 4) : (15 - y);
    const int q0 = qi * 128;
    const int bh = blockIdx.x, b = bh >> 4, h = bh & 15;
    const size_t tokBase = (size_t)b * Nseq;
    const int hcol = h * HD;

    // ---- Q fragments: direct global -> register (once per wave) ----
    bf16x8 qf[2][2];
    #pragma unroll
    for (int qt = 0; qt < 2; ++qt)
        #pragma unroll
        for (int ks = 0; ks < 2; ++ks)
            qf[qt][ks] = *(const bf16x8*)(
                Q + (tokBase + q0 + w*32 + qt*16 + c)*DIMD + hcol + (ks*4 + quad)*8);

    const int wrow0 = q0 + w*32;
    const int endw  = ((wrow0 + 31) >> 6) + 1;        // exact per-wave tiles
    const uint16_t* __restrict__ Kb = K + tokBase*DIMD + hcol;
    const uint16_t* __restrict__ Vb = Vt + ((size_t)bh*HD + c)*Nseq;

    f32x4  o[2][4] = {};
    float  l_lane[2] = {0.f, 0.f};

    for (int kt = 0; kt < endw; ++kt) {
        const int k0 = kt * 64;

        // ---- S^T = K.Q^T : C-layout row = kv (quad*4+r), col = q (c) ----
        f32x4 sv[2][4] = {};
        __builtin_amdgcn_s_setprio(1);
        #pragma unroll
        for (int nt = 0; nt < 4; ++nt)
            #pragma unroll
            for (int ks = 0; ks < 2; ++ks) {
                bf16x8 kf = *(const bf16x8*)(
                    Kb + (size_t)(k0 + nt*16 + c)*DIMD + (ks*4 + quad)*8);
                sv[0][nt] = __builtin_amdgcn_mfma_f32_16x16x32_bf16(kf, qf[0][ks], sv[0][nt], 0, 0, 0);
                sv[1][nt] = __builtin_amdgcn_mfma_f32_16x16x32_bf16(kf, qf[1][ks], sv[1][nt], 0, 0, 0);
            }
        __builtin_amdgcn_s_setprio(0);

        // ---- causal mask (diagonal tiles only; kv > q -> -inf) ----
        if (k0 + 63 > wrow0) {
            #pragma unroll
            for (int qt = 0; qt < 2; ++qt)
                #pragma unroll
                for (int nt = 0; nt < 4; ++nt)
                    #pragma unroll
                    for (int r = 0; r < 4; ++r) {
                        int kvg = k0 + nt*16 + quad*4 + r;
                        int qg  = wrow0 + qt*16 + c;
                        if (kvg > qg) sv[qt][nt][r] = -340.0f;
                    }
        }

        // ---- p = exp2(s); row-sum per lane; pack P^T as B-frags ----
        s16x4 pb[2][4];
        #pragma unroll
        for (int qt = 0; qt < 2; ++qt)
            #pragma unroll
            for (int nt = 0; nt < 4; ++nt) {
                float p0 = __builtin_amdgcn_exp2f(sv[qt][nt][0]);
                float p1 = __builtin_amdgcn_exp2f(sv[qt][nt][1]);
                float p2 = __builtin_amdgcn_exp2f(sv[qt][nt][2]);
                float p3 = __builtin_amdgcn_exp2f(sv[qt][nt][3]);
                l_lane[qt] += (p0 + p1) + (p2 + p3);
                union { uint32_t u[2]; s16x4 v; } pu;
                pu.u[0] = pk2(p0, p1);
                pu.u[1] = pk2(p2, p3);
                pb[qt][nt] = pu.v;
            }

        // ---- O^T += V^T.P^T  (K=16 steps; A = V^T rows direct from global) ----
        __builtin_amdgcn_s_setprio(1);
        #pragma unroll
        for (int s4 = 0; s4 < 4; ++s4)
            #pragma unroll
            for (int dt = 0; dt < 4; ++dt) {
                s16x4 vf = *(const s16x4*)(
                    Vb + (size_t)dt*16*Nseq + k0 + s4*16 + quad*4);
                o[0][dt] = __builtin_amdgcn_mfma_f32_16x16x16bf16_1k(vf, pb[0][s4], o[0][dt], 0, 0, 0);
                o[1][dt] = __builtin_amdgcn_mfma_f32_16x16x16bf16_1k(vf, pb[1][s4], o[1][dt], 0, 0, 0);
            }
        __builtin_amdgcn_s_setprio(0);
    }

    // ---- epilogue: reduce l over quads, scale, store O^T packed ----
    #pragma unroll
    for (int qt = 0; qt < 2; ++qt) {
        float l = l_lane[qt];
        l += __shfl_xor(l, 16);
        l += __shfl_xor(l, 32);
        float inv = 1.0f / l;
        int tok = (int)(q0 + w*32 + qt*16 + c);
        #pragma unroll
        for (int dt = 0; dt < 4; ++dt) {
            ushort4 o4;
            o4.x = f2bf(o[qt][dt][0] * inv);
            o4.y = f2bf(o[qt][dt][1] * inv);
            o4.z = f2bf(o[qt][dt][2] * inv);
            o4.w = f2bf(o[qt][dt][3] * inv);
            *(ushort4*)(O + (tokBase + tok)*DIMD + hcol + dt*16 + quad*4) = o4;
        }
    }
}

// ---------------------------------------------------------------------------
extern "C" void kernel_launch(void* const* d_in, const int* in_sizes, int n_in,
                              void* d_out, int out_size, void* d_ws, size_t ws_size,
                              hipStream_t stream) {
    const float* x  = (const float*)d_in[0];
    // d_in[1] = causal tril mask, deterministic -> handled analytically
    const float* Wq = (const float*)d_in[2];
    const float* Wk = (const float*)d_in[3];
    const float* Wv = (const float*)d_in[4];
    const float* Wo = (const float*)d_in[5];

    uint16_t* ws  = (uint16_t*)d_ws;
    uint16_t* xb  = ws;                      // x bf16 (later reused as attn out)
    uint16_t* wqb = ws + 8388608;            // Wq,Wk,Wv,Wo bf16 contiguous
    uint16_t* wob = wqb + 3*1048576;
    uint16_t* qb  = ws + 12582912;           // Q
    uint16_t* kb  = qb + 8388608;            // K
    uint16_t* vtb = kb + 8388608;            // V transposed per (b,h)
    uint16_t* ab  = xb;                      // attention output reuses xb

    cast_all<<<12288, 256, 0, stream>>>(x, Wq, Wk, Wv, Wo, ws);

    // grid (m, sec*8+n): XCD = m%8 pins each x-panel to one XCD's L2
    gemm_bt<uint16_t><<<dim3(64, 24), 256, 0, stream>>>(
        xb, wqb, qb, DIMD, DIMD, 8, (size_t)1048576, (size_t)8388608, vtb, 2);

    attn<<<dim3(64, 16), 256, 0, stream>>>(qb, kb, vtb, ab);

    gemm_bt<float><<<dim3(64, 8), 256, 0, stream>>>(
        ab, wob, (float*)d_out, DIMD, DIMD, 8, (size_t)0, (size_t)0, nullptr, -1);
}

// Round 6
// 254.999 us; speedup vs baseline: 1.4518x; 1.4518x over previous
//
#include <hip/hip_runtime.h>
#include <stdint.h>

#define Bq   4
#define Nseq 2048
#define NH   16
#define HD   64
#define DIMD 1024

typedef float  f32x4   __attribute__((ext_vector_type(4)));
typedef float  f32x16  __attribute__((ext_vector_type(16)));
typedef __bf16 bf16x8  __attribute__((ext_vector_type(8)));
typedef short  s16x4   __attribute__((ext_vector_type(4)));

typedef __attribute__((address_space(1))) void as1_void;
typedef __attribute__((address_space(3))) void as3_void;

static __device__ __forceinline__ uint16_t f2bf(float f) {
    uint32_t u = __builtin_bit_cast(uint32_t, f);
    u += 0x7fffu + ((u >> 16) & 1u);          // RNE
    return (uint16_t)(u >> 16);
}

// truncation-pack two fp32 -> packed bf16x2 (p>=0, 1-ulp bias, cancels in p/l)
static __device__ __forceinline__ uint32_t pk2(float a, float b) {
    uint32_t ua = __builtin_bit_cast(uint32_t, a);
    uint32_t ub = __builtin_bit_cast(uint32_t, b);
    return (ua >> 16) | (ub & 0xffff0000u);
}

static __device__ __forceinline__ void asyncLoad16(const uint16_t* g, uint16_t* l) {
    __builtin_amdgcn_global_load_lds((as1_void*)g, (as3_void*)l, 16, 0, 0);
}

static __device__ __forceinline__ void storeOut(float* p, float v)    { *p = v; }
static __device__ __forceinline__ void storeOut(uint16_t* p, float v) { *p = f2bf(v); }

// ---------------------------------------------------------------------------
// cast fp32 -> bf16 : x (8388608) then Wq,Wk,Wv,Wo (4 x 1048576), dst contiguous
// Wq is pre-scaled by SCALE*log2(e) so attention can use exp2 on raw QK dots.
// ---------------------------------------------------------------------------
__global__ void cast_all(const float* __restrict__ x,
                         const float* __restrict__ wq, const float* __restrict__ wk,
                         const float* __restrict__ wv, const float* __restrict__ wo,
                         uint16_t* __restrict__ dst) {
    size_t i = ((size_t)blockIdx.x * blockDim.x + threadIdx.x) * 4;  // elem idx
    const float* src; size_t off; float scale = 1.0f;
    if (i < 8388608) { src = x; off = i; }
    else {
        size_t wI = i - 8388608;
        size_t wi = wI >> 20;
        off = wI & 1048575;
        src = (wi == 0) ? wq : (wi == 1) ? wk : (wi == 2) ? wv : wo;
        if (wi == 0) scale = 0.18033688011112042f;   // (1/sqrt(64)) * log2(e)
    }
    float4 v = *(const float4*)(src + off);
    ushort4 o;
    o.x = f2bf(v.x * scale); o.y = f2bf(v.y * scale);
    o.z = f2bf(v.z * scale); o.w = f2bf(v.w * scale);
    *(ushort4*)(dst + i) = o;
}

// ---------------------------------------------------------------------------
// QKV GEMM: faithful port of the verified 256^2 8-phase schedule (m201).
//   C[m][n] = sum_k A[m][k]*W[n][k], K=1024, BK=64, 512 thr = 8 waves (2Mx4N).
// Per-wave 128x64 out = 8x4 frags of 16x16; phase = one C-quadrant (mh,nh) =
// 16 x mfma_f32_16x16x32_bf16. ds-reads per K-tile: 12/4/8/0 (A-half 8, B-half
// 4, held in regs across the quadrant pair). One half-tile (2 global_load_lds
// of 8 KB) staged per phase; counted vmcnt(4) ONLY at phases 4 and 8.
// LDS 128 KiB: A[2dbuf][2mh][2wm][64][64], B[2dbuf][2nh][4wn][32][64] --
// half-tiles grouped so each equals one phase's dead region. Full FIFO-queue +
// liveness audit (per-phase):
//   stage P1:A1'(T+1)->b1  P2:B1'(T+1)->b1  P3:A0(T+2)->b0  P4:B0(T+2)->b0
//         P5:A1(T+2)->b0   P6:B1(T+2)->b0   P7:A0'(T+3)->b1 P8:B0'(T+3)->b1
//   vmcnt(4)@P4 forces all T+1 (read P5-P8); vmcnt(4)@P8 forces all T+2
//   (read P1-P3 next iter); every stage >= its region's dead-phase.
// 16-row fragments make the chunk^(row&7) swizzle 2-way max (free) vs the
// 4-way of 32-row frags (the 6.3M conflict counter on gemm_bt).
// sched_barrier(0) at phase boundaries pins +/-1-phase motion (rule #18);
// each +/-1 hoist audited race-free. Grid (32,12): xcd = x%8 pins m-panels.
// sec = y>>2 in {Q,K,V}; V written transposed vt[(b*16+h)*64+d][tok].
// C/D 16x16 layout: col = lane&15, row = (lane>>4)*4 + reg.
// ---------------------------------------------------------------------------
__global__ __launch_bounds__(512, 2) void gemm_qkv8(
    const uint16_t* __restrict__ A, const uint16_t* __restrict__ W0,
    uint16_t* __restrict__ C0, uint16_t* __restrict__ vtb)
{
    __shared__ __align__(16) uint16_t Asm[2][2][8192];   // [dbuf][mh][wm*4096+r*64+c]
    __shared__ __align__(16) uint16_t Bsm[2][2][8192];   // [dbuf][nh][wn*2048+r*64+c]

    const int t = threadIdx.x, lane = t & 63, w = t >> 6;
    const int wm = w >> 2, wn = w & 3;                   // 2 x 4 wave grid
    const int ln = lane & 15, l4 = lane >> 4;

    const int m0  = blockIdx.x * 256;
    const int sec = blockIdx.y >> 2;                     // 0=Q 1=K 2=V
    const int n0  = (blockIdx.y & 3) * 256;
    const uint16_t* __restrict__ Wp = W0 + (size_t)sec * 1048576;

    // staging: 512 thr x 16B = 64 flat rows per load; chunk pre-swizzled
    const int srow = t >> 3;                             // 0..63
    const int sg   = (t & 7) ^ (srow & 7);
    const uint16_t* Abase = A  + (size_t)(m0 + srow)*DIMD + sg*8;
    const uint16_t* Bbase = Wp + (size_t)(n0 + (srow>>5)*64 + (srow&31))*DIMD + sg*8;

    // A half mh: rows {j*128 + mh*64 + 0..63}, j = wm-block; B half nh:
    // rows {(2j+(srow>>5))*64 + nh*32 + (srow&31)}
#define SA8(mh_, j_, buf_, kk_) asyncLoad16(Abase + (size_t)((j_)*128 + (mh_)*64)*DIMD + (kk_), \
        &Asm[buf_][mh_][(j_)*4096 + t*8])
#define SB8(nh_, j_, buf_, kk_) asyncLoad16(Bbase + (size_t)((j_)*128 + (nh_)*32)*DIMD + (kk_), \
        &Bsm[buf_][nh_][(j_)*4096 + t*8])

    // prologue: T0 -> buf0 (4 ht), A0',B0'(T1) -> buf1 (2 ht, stay in flight)
    SA8(0,0,0,0); SA8(0,1,0,0);
    SB8(0,0,0,0); SB8(0,1,0,0);
    SA8(1,0,0,0); SA8(1,1,0,0);
    SB8(1,0,0,0); SB8(1,1,0,0);
    SA8(0,0,1,64); SA8(0,1,1,64);
    SB8(0,0,1,64); SB8(0,1,1,64);
    asm volatile("s_waitcnt vmcnt(4)" ::: "memory");
    __builtin_amdgcn_s_barrier();

    const int awo = wm*4096 + ln*64;
    const int bwo = wn*2048 + ln*64;
    const int cs0 = ( l4      ^ (ln & 7)) * 8;           // kstep 0 chunk
    const int cs1 = ((4 + l4) ^ (ln & 7)) * 8;           // kstep 1 chunk

    bf16x8 af[4][2], bf0[2][2], bf1[2][2];
    f32x4 acc[8][4] = {};

#define LDA8(mh_, buf_)                                                        \
    _Pragma("unroll")                                                          \
    for (int mf = 0; mf < 4; ++mf) {                                           \
        af[mf][0] = *(const bf16x8*)(&Asm[buf_][mh_][awo + mf*1024 + cs0]);    \
        af[mf][1] = *(const bf16x8*)(&Asm[buf_][mh_][awo + mf*1024 + cs1]);    \
    }
#define LDB8(nh_, buf_, BF)                                                    \
    _Pragma("unroll")                                                          \
    for (int nf = 0; nf < 2; ++nf) {                                           \
        BF[nf][0] = *(const bf16x8*)(&Bsm[buf_][nh_][bwo + nf*1024 + cs0]);    \
        BF[nf][1] = *(const bf16x8*)(&Bsm[buf_][nh_][bwo + nf*1024 + cs1]);    \
    }
#define MFMA16(mh_, nh_, BF)                                                   \
    _Pragma("unroll")                                                          \
    for (int mf = 0; mf < 4; ++mf)                                             \
        _Pragma("unroll")                                                      \
        for (int nf = 0; nf < 2; ++nf) {                                       \
            acc[(mh_)*4+mf][(nh_)*2+nf] = __builtin_amdgcn_mfma_f32_16x16x32_bf16( \
                af[mf][0], BF[nf][0], acc[(mh_)*4+mf][(nh_)*2+nf], 0,0,0);     \
            acc[(mh_)*4+mf][(nh_)*2+nf] = __builtin_amdgcn_mfma_f32_16x16x32_bf16( \
                af[mf][1], BF[nf][1], acc[(mh_)*4+mf][(nh_)*2+nf], 0,0,0);     \
        }
#define BARR()  __builtin_amdgcn_s_barrier()
#define SCB0()  __builtin_amdgcn_sched_barrier(0)
#define LGKM()  asm volatile("s_waitcnt lgkmcnt(0)" ::: "memory")
#define PRIO1() __builtin_amdgcn_s_setprio(1)
#define PRIO0() __builtin_amdgcn_s_setprio(0)

    #pragma unroll 1
    for (int i = 0; i < 8; ++i) {                        // iter = K-tiles 2i,2i+1
        const int kk1 = i*128 + 64, kk2 = i*128 + 128, kk3 = i*128 + 192;
        const bool pf = (i < 7);

        // -------- P1: buf0 (mh0,nh0); reads 12; stage A1'(T+1)->b1 --------
        LDA8(0,0); LDB8(0,0,bf0);
        SA8(1,0,1,kk1); SA8(1,1,1,kk1);
        BARR(); LGKM(); SCB0();
        PRIO1(); MFMA16(0,0,bf0); PRIO0();
        SCB0(); BARR();

        // -------- P2: buf0 (mh0,nh1); reads 4; stage B1'(T+1)->b1 --------
        LDB8(1,0,bf1);
        SB8(1,0,1,kk1); SB8(1,1,1,kk1);
        BARR(); LGKM(); SCB0();
        PRIO1(); MFMA16(0,1,bf1); PRIO0();
        SCB0(); BARR();

        // -------- P3: buf0 (mh1,nh0); reads 8; stage A0(T+2)->b0 --------
        LDA8(1,0);
        if (pf) { SA8(0,0,0,kk2); SA8(0,1,0,kk2); }
        BARR(); LGKM(); SCB0();
        PRIO1(); MFMA16(1,0,bf0); PRIO0();
        SCB0(); BARR();

        // -------- P4: buf0 (mh1,nh1); reads 0; stage B0(T+2)->b0; vmcnt --------
        if (pf) { SB8(0,0,0,kk2); SB8(0,1,0,kk2); }
        BARR(); SCB0();
        PRIO1(); MFMA16(1,1,bf1); PRIO0();
        SCB0();
        if (pf) { asm volatile("s_waitcnt vmcnt(4)" ::: "memory"); }
        else    { asm volatile("s_waitcnt vmcnt(0)" ::: "memory"); }
        BARR();

        // -------- P5: buf1 (mh0,nh0); reads 12; stage A1(T+2)->b0 --------
        LDA8(0,1); LDB8(0,1,bf0);
        if (pf) { SA8(1,0,0,kk2); SA8(1,1,0,kk2); }
        BARR(); LGKM(); SCB0();
        PRIO1(); MFMA16(0,0,bf0); PRIO0();
        SCB0(); BARR();

        // -------- P6: buf1 (mh0,nh1); reads 4; stage B1(T+2)->b0 --------
        LDB8(1,1,bf1);
        if (pf) { SB8(1,0,0,kk2); SB8(1,1,0,kk2); }
        BARR(); LGKM(); SCB0();
        PRIO1(); MFMA16(0,1,bf1); PRIO0();
        SCB0(); BARR();

        // -------- P7: buf1 (mh1,nh0); reads 8; stage A0'(T+3)->b1 --------
        LDA8(1,1);
        if (pf) { SA8(0,0,1,kk3); SA8(0,1,1,kk3); }
        BARR(); LGKM(); SCB0();
        PRIO1(); MFMA16(1,0,bf0); PRIO0();
        SCB0(); BARR();

        // -------- P8: buf1 (mh1,nh1); reads 0; stage B0'(T+3)->b1; vmcnt --------
        if (pf) { SB8(0,0,1,kk3); SB8(0,1,1,kk3); }
        BARR(); SCB0();
        PRIO1(); MFMA16(1,1,bf1); PRIO0();
        SCB0();
        if (pf) { asm volatile("s_waitcnt vmcnt(4)" ::: "memory"); BARR(); }
    }

#undef SA8
#undef SB8
#undef LDA8
#undef LDB8
#undef MFMA16

    // ---- epilogue: C/D 16x16 layout col = ln, row = l4*4 + r ----
    if (sec == 2) {
        #pragma unroll
        for (int mf = 0; mf < 8; ++mf)
            #pragma unroll
            for (int nf = 0; nf < 4; ++nf) {
                int colg = n0 + wn*64 + nf*16 + ln;              // dim
                int hh = colg >> 6, dd = colg & 63;
                int rowg = m0 + wm*128 + mf*16 + l4*4;           // token base
                int bb = rowg >> 11, nn = rowg & 2047;
                ushort4 o4;
                o4.x = f2bf(acc[mf][nf][0]);
                o4.y = f2bf(acc[mf][nf][1]);
                o4.z = f2bf(acc[mf][nf][2]);
                o4.w = f2bf(acc[mf][nf][3]);
                *(ushort4*)(vtb + ((size_t)((bb*NH + hh)*HD + dd))*Nseq + nn) = o4;
            }
    } else {
        uint16_t* C = C0 + (size_t)sec * 8388608;
        #pragma unroll
        for (int mf = 0; mf < 8; ++mf)
            #pragma unroll
            for (int nf = 0; nf < 4; ++nf) {
                int col = n0 + wn*64 + nf*16 + ln;
                int row = m0 + wm*128 + mf*16 + l4*4;
                #pragma unroll
                for (int r = 0; r < 4; ++r)
                    C[(size_t)(row + r)*DIMD + col] = f2bf(acc[mf][nf][r]);
            }
    }
}

// ---------------------------------------------------------------------------
// GEMM  C[m][n] = sum_k A[m][k] * W[n][k]   (B^T layout, both row-major over K)
// 128x128 tile, BK=64, 256 thr = 4 waves (2x2) -- retained for the output
// projection (N=1024; 512 blocks).
// ---------------------------------------------------------------------------
template <typename OutT>
__global__ __launch_bounds__(256) void gemm_bt(
    const uint16_t* __restrict__ A, const uint16_t* __restrict__ W0,
    OutT* __restrict__ C0, int K, int Nld, int blocksPerSec,
    size_t wSecStride, size_t cSecStride, uint16_t* __restrict__ vtb, int vSec)
{
    __shared__ __align__(16) uint16_t As[128*64];
    __shared__ __align__(16) uint16_t Bs[128*64];

    const int t = threadIdx.x, lane = t & 63, w = t >> 6;
    const int wr = w >> 1, wc = w & 1;
    const int half = lane >> 5, ml = lane & 31;

    const int m0  = blockIdx.x * 128;
    const int sec = blockIdx.y / blocksPerSec;
    const int n0  = (blockIdx.y % blocksPerSec) * 128;
    const uint16_t* Wp = W0 + (size_t)sec * wSecStride;
    OutT* C = C0 + (size_t)sec * cSecStride;

    int srow[4], sg[4];
    #pragma unroll
    for (int i = 0; i < 4; ++i) {
        int s = t + 256*i;
        srow[i] = s >> 3;
        sg[i]   = (s & 7) ^ (srow[i] & 7);
    }

    int arow[2], brow[2];
    #pragma unroll
    for (int i = 0; i < 2; ++i) {
        arow[i] = wr*64 + i*32 + ml;
        brow[i] = wc*64 + i*32 + ml;
    }

    f32x16 acc[2][2] = {};

    for (int k0 = 0; k0 < K; k0 += 64) {
        __syncthreads();
        #pragma unroll
        for (int i = 0; i < 4; ++i) {
            asyncLoad16(A  + (size_t)(m0 + srow[i])*K + k0 + sg[i]*8,
                        As + (size_t)(w*64 + 256*i)*8);
            asyncLoad16(Wp + (size_t)(n0 + srow[i])*K + k0 + sg[i]*8,
                        Bs + (size_t)(w*64 + 256*i)*8);
        }
        __syncthreads();

        #pragma unroll
        for (int s = 0; s < 4; ++s) {            // k-step of 16
            const int chunk = s*2 + half;
            bf16x8 af[2], bfr[2];
            #pragma unroll
            for (int i = 0; i < 2; ++i) {
                int m = arow[i];
                af[i]  = *(const bf16x8*)(As + (size_t)(m*8 + (chunk ^ (m & 7)))*8);
                int n = brow[i];
                bfr[i] = *(const bf16x8*)(Bs + (size_t)(n*8 + (chunk ^ (n & 7)))*8);
            }
            #pragma unroll
            for (int mt = 0; mt < 2; ++mt)
                #pragma unroll
                for (int nt = 0; nt < 2; ++nt)
                    acc[mt][nt] = __builtin_amdgcn_mfma_f32_32x32x16_bf16(
                        af[mt], bfr[nt], acc[mt][nt], 0, 0, 0);
        }
    }

    if (vtb != nullptr && sec == vSec) {
        #pragma unroll
        for (int mt = 0; mt < 2; ++mt)
            #pragma unroll
            for (int nt = 0; nt < 2; ++nt) {
                int colg = n0 + wc*64 + nt*32 + ml;               // dim
                int hh = colg >> 6, dd = colg & 63;
                #pragma unroll
                for (int g = 0; g < 4; ++g) {
                    int rowg = m0 + wr*64 + mt*32 + 8*g + 4*half; // token (+reg&3)
                    int bb = rowg >> 11, nn = rowg & 2047;
                    ushort4 o4;
                    o4.x = f2bf(acc[mt][nt][4*g + 0]);
                    o4.y = f2bf(acc[mt][nt][4*g + 1]);
                    o4.z = f2bf(acc[mt][nt][4*g + 2]);
                    o4.w = f2bf(acc[mt][nt][4*g + 3]);
                    *(ushort4*)(vtb + ((size_t)((bb*NH + hh)*HD + dd))*Nseq + nn) = o4;
                }
            }
    } else {
        #pragma unroll
        for (int mt = 0; mt < 2; ++mt)
            #pragma unroll
            for (int nt = 0; nt < 2; ++nt) {
                int col = n0 + wc*64 + nt*32 + ml;
                #pragma unroll
                for (int r = 0; r < 16; ++r) {
                    int row = m0 + wr*64 + mt*32 + (r & 3) + 8*(r >> 2) + 4*half;
                    storeOut(&C[(size_t)row * Nld + col], acc[mt][nt][r]);
                }
            }
    }
}

// ---------------------------------------------------------------------------
// Flash attention, causal, no-max online softmax, S^T formulation (R4 version:
// best measured attn ~67.7us). Triple-buffered K/V staging + counted-vmcnt raw
// barriers; PV on mfma_16x16x16bf16_1k (register P^T, no LDS round-trip).
// R5's no-LDS variant regressed 2.8x (per-lane row-gather operand loads).
// ---------------------------------------------------------------------------
__global__ __launch_bounds__(256, 3) void attn(
    const uint16_t* __restrict__ Q, const uint16_t* __restrict__ K,
    const uint16_t* __restrict__ Vt, uint16_t* __restrict__ O)
{
    __shared__ __align__(16) uint16_t Kb[3][64*64];   // 24 KB (first 16 KB = Q scratch)
    __shared__ __align__(16) uint16_t Vb[3][64*64];   // 24 KB (V^T tiles, rows=d)

    const int t = threadIdx.x, lane = t & 63, w = t >> 6;
    const int quad = lane >> 4, c = lane & 15;
    const int y = blockIdx.y;
    const int qi = (y < 4) ? (15 - y) : (y < 8) ? (y + 4) : (y < 12) ? (y - 4) : (15 - y);
    const int q0 = qi * 128;
    const int bh = blockIdx.x, b = bh >> 4, h = bh & 15;
    const size_t tokBase = (size_t)b * Nseq;
    const int hcol = h * HD;
    uint16_t* Qs = (uint16_t*)Kb;                    // 16 KB scratch (Kb[0..1])

    #define STAGE_KV(k0_, buf_)                                             \
        _Pragma("unroll")                                                    \
        for (int i = 0; i < 2; ++i) {                                        \
            int s = t + 256*i;                                               \
            int row = s >> 3, gg = (s & 7) ^ (row & 7);                      \
            asyncLoad16(K + (tokBase + (k0_) + row)*DIMD + hcol + gg*8,      \
                        Kb[buf_] + (size_t)(w*64 + 256*i)*8);                \
            asyncLoad16(Vt + ((size_t)bh*HD + row)*Nseq + (k0_) + gg*8,      \
                        Vb[buf_] + (size_t)(w*64 + 256*i)*8);                \
        }

    // ---- stage Q (128x64) through scratch, grab fragments, then free it ----
    #pragma unroll
    for (int i = 0; i < 4; ++i) {
        int s = t + 256*i;
        int row = s >> 3, gg = (s & 7) ^ (row & 7);
        asyncLoad16(Q + (tokBase + q0 + row)*DIMD + hcol + gg*8,
                    Qs + (size_t)(w*64 + 256*i)*8);
    }
    __syncthreads();                                  // Q landed
    bf16x8 qf[2][2];
    #pragma unroll
    for (int qt = 0; qt < 2; ++qt)
        #pragma unroll
        for (int ks = 0; ks < 2; ++ks) {
            int row = w*32 + qt*16 + c;
            int pos = (ks*4 + quad) ^ (row & 7);
            qf[qt][ks] = *(const bf16x8*)(Qs + (size_t)(row*8 + pos)*8);
        }
    __syncthreads();                                  // all reads done, scratch free

    const int wrow0 = q0 + w*32;
    const int end = 2*qi + 2;                         // always >= 2
    STAGE_KV(0, 0);                                   // tiles 0 and 1 in flight
    STAGE_KV(64, 1);

    f32x4  o[2][4] = {};
    float  l_lane[2] = {0.f, 0.f};
    int b0 = 0, b1 = 1, b2 = 2;                       // cur / next / stage-target

    for (int kt = 0; kt < end; ++kt) {
        const int k0 = kt * 64;

        // buf[b0] (tile kt, staged 2 iters ago) must be ready; tile kt+1's
        // 4 loads stay in flight across the barrier.
        if (kt + 1 < end) { asm volatile("s_waitcnt vmcnt(4)\n\ts_barrier" ::: "memory"); }
        else              { asm volatile("s_waitcnt vmcnt(0)\n\ts_barrier" ::: "memory"); }

        if (kt + 2 < end) { STAGE_KV((kt+2)*64, b2); }

        if (k0 <= wrow0 + 31) {                       // wave not fully above diag
            const uint16_t* Ks = Kb[b0];
            const uint16_t* Vs = Vb[b0];

            // ---- S^T = K.Q^T : C-layout row = kv (quad*4+r), col = q (c) ----
            f32x4 sv[2][4] = {};
            __builtin_amdgcn_s_setprio(1);
            #pragma unroll
            for (int nt = 0; nt < 4; ++nt)
                #pragma unroll
                for (int ks = 0; ks < 2; ++ks) {
                    int row = nt*16 + c;
                    int pos = (ks*4 + quad) ^ (row & 7);
                    bf16x8 kf = *(const bf16x8*)(Ks + (size_t)(row*8 + pos)*8);
                    sv[0][nt] = __builtin_amdgcn_mfma_f32_16x16x32_bf16(kf, qf[0][ks], sv[0][nt], 0, 0, 0);
                    sv[1][nt] = __builtin_amdgcn_mfma_f32_16x16x32_bf16(kf, qf[1][ks], sv[1][nt], 0, 0, 0);
                }
            __builtin_amdgcn_s_setprio(0);

            // ---- causal mask (diagonal tiles only; kv > q -> -inf) ----
            if (k0 + 63 > wrow0) {
                #pragma unroll
                for (int qt = 0; qt < 2; ++qt)
                    #pragma unroll
                    for (int nt = 0; nt < 4; ++nt)
                        #pragma unroll
                        for (int r = 0; r < 4; ++r) {
                            int kvg = k0 + nt*16 + quad*4 + r;
                            int qg  = wrow0 + qt*16 + c;
                            if (kvg > qg) sv[qt][nt][r] = -340.0f;
                        }
            }

            // ---- p = exp2(s); row-sum per lane; pack P^T as B-frags ----
            s16x4 pb[2][4];
            #pragma unroll
            for (int qt = 0; qt < 2; ++qt)
                #pragma unroll
                for (int nt = 0; nt < 4; ++nt) {
                    float p0 = __builtin_amdgcn_exp2f(sv[qt][nt][0]);
                    float p1 = __builtin_amdgcn_exp2f(sv[qt][nt][1]);
                    float p2 = __builtin_amdgcn_exp2f(sv[qt][nt][2]);
                    float p3 = __builtin_amdgcn_exp2f(sv[qt][nt][3]);
                    l_lane[qt] += (p0 + p1) + (p2 + p3);
                    union { uint32_t u[2]; s16x4 v; } pu;
                    pu.u[0] = pk2(p0, p1);
                    pu.u[1] = pk2(p2, p3);
                    pb[qt][nt] = pu.v;
                }

            // ---- O^T += V^T.P^T  (K=16 steps; A=V^T rows from LDS b64) ----
            __builtin_amdgcn_s_setprio(1);
            #pragma unroll
            for (int s4 = 0; s4 < 4; ++s4)
                #pragma unroll
                for (int dt = 0; dt < 4; ++dt) {
                    int row = dt*16 + c;                    // d
                    int chunk = s4*2 + (quad >> 1);
                    int pos = chunk ^ (row & 7);
                    s16x4 vf = *(const s16x4*)(Vs + (size_t)(row*8 + pos)*8 + (quad & 1)*4);
                    o[0][dt] = __builtin_amdgcn_mfma_f32_16x16x16bf16_1k(vf, pb[0][s4], o[0][dt], 0, 0, 0);
                    o[1][dt] = __builtin_amdgcn_mfma_f32_16x16x16bf16_1k(vf, pb[1][s4], o[1][dt], 0, 0, 0);
                }
            __builtin_amdgcn_s_setprio(0);
        }

        int tmp = b0; b0 = b1; b1 = b2; b2 = tmp;     // rotate buffers
    }

    // ---- epilogue: reduce l over quads, scale, store O^T packed ----
    #pragma unroll
    for (int qt = 0; qt < 2; ++qt) {
        float l = l_lane[qt];
        l += __shfl_xor(l, 16);
        l += __shfl_xor(l, 32);
        float inv = 1.0f / l;
        int tok = (int)(q0 + w*32 + qt*16 + c);
        #pragma unroll
        for (int dt = 0; dt < 4; ++dt) {
            ushort4 o4;
            o4.x = f2bf(o[qt][dt][0] * inv);
            o4.y = f2bf(o[qt][dt][1] * inv);
            o4.z = f2bf(o[qt][dt][2] * inv);
            o4.w = f2bf(o[qt][dt][3] * inv);
            *(ushort4*)(O + (tokBase + tok)*DIMD + hcol + dt*16 + quad*4) = o4;
        }
    }
    #undef STAGE_KV
}

// ---------------------------------------------------------------------------
extern "C" void kernel_launch(void* const* d_in, const int* in_sizes, int n_in,
                              void* d_out, int out_size, void* d_ws, size_t ws_size,
                              hipStream_t stream) {
    const float* x  = (const float*)d_in[0];
    // d_in[1] = causal tril mask, deterministic -> handled analytically
    const float* Wq = (const float*)d_in[2];
    const float* Wk = (const float*)d_in[3];
    const float* Wv = (const float*)d_in[4];
    const float* Wo = (const float*)d_in[5];

    uint16_t* ws  = (uint16_t*)d_ws;
    uint16_t* xb  = ws;                      // x bf16 (later reused as attn out)
    uint16_t* wqb = ws + 8388608;            // Wq,Wk,Wv,Wo bf16 contiguous
    uint16_t* wob = wqb + 3*1048576;
    uint16_t* qb  = ws + 12582912;           // Q
    uint16_t* kb  = qb + 8388608;            // K
    uint16_t* vtb = kb + 8388608;            // V transposed per (b,h)
    uint16_t* ab  = xb;                      // attention output reuses xb

    cast_all<<<12288, 256, 0, stream>>>(x, Wq, Wk, Wv, Wo, ws);

    // QKV: 256^2 8-phase counted-vmcnt kernel; grid (32,12), xcd = x%8.
    gemm_qkv8<<<dim3(32, 12), 512, 0, stream>>>(xb, wqb, qb, vtb);

    attn<<<dim3(64, 16), 256, 0, stream>>>(qb, kb, vtb, ab);

    gemm_bt<float><<<dim3(64, 8), 256, 0, stream>>>(
        ab, wob, (float*)d_out, DIMD, DIMD, 8, (size_t)0, (size_t)0, nullptr, -1);
}

// Round 7
// 247.658 us; speedup vs baseline: 1.4949x; 1.0296x over previous
//
#include <hip/hip_runtime.h>
#include <stdint.h>

#define Bq   4
#define Nseq 2048
#define NH   16
#define HD   64
#define DIMD 1024

typedef float  f32x4   __attribute__((ext_vector_type(4)));
typedef float  f32x16  __attribute__((ext_vector_type(16)));
typedef __bf16 bf16x8  __attribute__((ext_vector_type(8)));
typedef short  s16x4   __attribute__((ext_vector_type(4)));

typedef __attribute__((address_space(1))) void as1_void;
typedef __attribute__((address_space(3))) void as3_void;

static __device__ __forceinline__ uint16_t f2bf(float f) {
    uint32_t u = __builtin_bit_cast(uint32_t, f);
    u += 0x7fffu + ((u >> 16) & 1u);          // RNE
    return (uint16_t)(u >> 16);
}

// truncation-pack two fp32 -> packed bf16x2 (p>=0, 1-ulp bias, cancels in p/l)
static __device__ __forceinline__ uint32_t pk2(float a, float b) {
    uint32_t ua = __builtin_bit_cast(uint32_t, a);
    uint32_t ub = __builtin_bit_cast(uint32_t, b);
    return (ua >> 16) | (ub & 0xffff0000u);
}

static __device__ __forceinline__ void asyncLoad16(const uint16_t* g, uint16_t* l) {
    __builtin_amdgcn_global_load_lds((as1_void*)g, (as3_void*)l, 16, 0, 0);
}

static __device__ __forceinline__ void storeOut(float* p, float v)    { *p = v; }
static __device__ __forceinline__ void storeOut(uint16_t* p, float v) { *p = f2bf(v); }

// ---------------------------------------------------------------------------
// cast fp32 -> bf16 : x (8388608) then Wq,Wk,Wv,Wo (4 x 1048576), dst contiguous
// Wq is pre-scaled by SCALE*log2(e) so attention can use exp2 on raw QK dots.
// ---------------------------------------------------------------------------
__global__ void cast_all(const float* __restrict__ x,
                         const float* __restrict__ wq, const float* __restrict__ wk,
                         const float* __restrict__ wv, const float* __restrict__ wo,
                         uint16_t* __restrict__ dst) {
    size_t i = ((size_t)blockIdx.x * blockDim.x + threadIdx.x) * 4;  // elem idx
    const float* src; size_t off; float scale = 1.0f;
    if (i < 8388608) { src = x; off = i; }
    else {
        size_t wI = i - 8388608;
        size_t wi = wI >> 20;
        off = wI & 1048575;
        src = (wi == 0) ? wq : (wi == 1) ? wk : (wi == 2) ? wv : wo;
        if (wi == 0) scale = 0.18033688011112042f;   // (1/sqrt(64)) * log2(e)
    }
    float4 v = *(const float4*)(src + off);
    ushort4 o;
    o.x = f2bf(v.x * scale); o.y = f2bf(v.y * scale);
    o.z = f2bf(v.z * scale); o.w = f2bf(v.w * scale);
    *(ushort4*)(dst + i) = o;
}

// ---------------------------------------------------------------------------
// QKV GEMM: R6's verified 8-phase schedule (in-kernel ~910 TF, conflicts 0)
// re-shaped to BM=128 x BN=384 so the grid divides the CU count:
//   grid (64, 8) = 512 blocks = 2 EXACT rounds at 1 block/CU (128 KiB LDS) --
//   R6's 256^2 grid was 384 blocks = 1.5 rounds (75% tail, the whole loss).
// 512 thr = 8 waves (2M x 4N); per-wave 64x96 = 4mf x 6nf frags of 16x16.
// Phase = quadrant (mh: 2mf, nh: 3nf) x 2 ksteps = 12 x mfma_16x16x32_bf16.
// ds-reads per K-tile: 10/6/4/0.  Staging units per K-tile: 8 (A: 2 mh-pure
// 64-row units, B: 6 nh-pure 64-row units) => IDENTICAL unit count to R6, so
// the phase plan keeps exactly 2 units/phase and the same vmcnt numbers:
//   P1: A-mh1'(T+1), B-nh1'u0(T+1)   P2: B-nh1'u1,u2(T+1)
//   P3: A-mh0(T+2),  B-nh0 u0(T+2)   P4: B-nh0 u1,u2(T+2)  + vmcnt(4)
//   P5: A-mh1(T+2),  B-nh1 u0(T+2)   P6: B-nh1 u1,u2(T+2)
//   P7: A-mh0'(T+3), B-nh0'u0(T+3)   P8: B-nh0'u1,u2(T+3)  + vmcnt(4)
// FIFO audit: steady in-flight at P4/P8-end = 12; vmcnt(4) forces oldest 8 =
// all of T+1 / T+2 resp. Liveness: every staged region's last read is >= 1
// barrier-pair earlier (audited per phase). Prologue 8+4 units + vmcnt(4)
// reproduces the steady-state invariant (4 in flight at P1).
// Swizzle: chunk ^ (row&7); all fragment rows == ln (mod 8) on write & read
// (48,32,16,64 all == 0 mod 8) -> conflict-free (R6-measured 0).
// BN=384 straddles section boundaries: epilogue branches per fragment column:
//   col < 2048 -> row-major into qb/kb (adjacent buffers, (col>>10) selects);
//   col >= 2048 -> V transposed vt[(bb*1024 + (col-2048))][token].
// C/D 16x16 layout: col = lane&15, row = (lane>>4)*4 + reg.
// ---------------------------------------------------------------------------
__global__ __launch_bounds__(512, 2) void gemm_qkv384(
    const uint16_t* __restrict__ A, const uint16_t* __restrict__ W0,
    uint16_t* __restrict__ C0, uint16_t* __restrict__ vtb)
{
    __shared__ __align__(16) uint16_t Asm[2][2][4096];    // [buf][mh][64 rows x 64]
    __shared__ __align__(16) uint16_t Bsm[2][2][12288];   // [buf][nh][3 units x 64 x 64]

    const int t = threadIdx.x, lane = t & 63, w = t >> 6;
    const int wm = w >> 2, wn = w & 3;                    // 2 x 4 wave grid
    const int ln = lane & 15, l4 = lane >> 4;

    const int m0 = blockIdx.x * 128;
    const int n0 = blockIdx.y * 384;                      // global over Q|K|V rows

    // staging: 512 thr x 16B = one 64-row unit; chunk pre-swizzled
    const int srow = t >> 3;                              // 0..63
    const int sg   = (t & 7) ^ (srow & 7);
    // A unit(mh): row = m0 + (srow>>5)*64 + mh*32 + (srow&31)
    const uint16_t* aBase = A + (size_t)(m0 + (srow >> 5)*64 + (srow & 31))*DIMD + sg*8;
    // B unit(nh,j): f = j*64+srow; wn_f = f/48; row = n0 + wn_f*96 + nh*48 + f%48
    const uint16_t* bBase[3];
    #pragma unroll
    for (int j = 0; j < 3; ++j) {
        int f = j*64 + srow;
        int wnf = f / 48, off = f % 48;
        bBase[j] = W0 + (size_t)(n0 + wnf*96 + off)*DIMD + sg*8;
    }

#define SA(mh_, buf_, kk_) asyncLoad16(aBase + (size_t)(mh_)*32*DIMD + (kk_), \
        &Asm[buf_][mh_][t*8])
#define SB(nh_, j_, buf_, kk_) asyncLoad16(bBase[j_] + (size_t)(nh_)*48*DIMD + (kk_), \
        &Bsm[buf_][nh_][(j_)*4096 + t*8])

    // prologue: T0 -> buf0 (8 units), then T1 first half (A-mh0', B-nh0') -> buf1
    SA(0,0,0); SA(1,0,0);
    SB(0,0,0,0); SB(0,1,0,0); SB(0,2,0,0);
    SB(1,0,0,0); SB(1,1,0,0); SB(1,2,0,0);
    SA(0,1,64);
    SB(0,0,1,64); SB(0,1,1,64); SB(0,2,1,64);
    asm volatile("s_waitcnt vmcnt(4)" ::: "memory");
    __builtin_amdgcn_s_barrier();

    const int cs0 = ( l4      ^ (ln & 7)) * 8;            // kstep 0 chunk
    const int cs1 = ((4 + l4) ^ (ln & 7)) * 8;            // kstep 1 chunk
    const int awo = wm*2048 + ln*64;                      // + mf*1024 + cs
    const int bwo = wn*3072 + ln*64;                      // + nf*1024 + cs

    bf16x8 af[2][2], bf0[3][2], bf1[3][2];
    f32x4 acc[4][6] = {};

#define LDA(mh_, buf_)                                                         \
    _Pragma("unroll")                                                          \
    for (int mf = 0; mf < 2; ++mf) {                                           \
        af[mf][0] = *(const bf16x8*)(&Asm[buf_][mh_][awo + mf*1024 + cs0]);    \
        af[mf][1] = *(const bf16x8*)(&Asm[buf_][mh_][awo + mf*1024 + cs1]);    \
    }
#define LDB(nh_, buf_, BF)                                                     \
    _Pragma("unroll")                                                          \
    for (int nf = 0; nf < 3; ++nf) {                                           \
        BF[nf][0] = *(const bf16x8*)(&Bsm[buf_][nh_][bwo + nf*1024 + cs0]);    \
        BF[nf][1] = *(const bf16x8*)(&Bsm[buf_][nh_][bwo + nf*1024 + cs1]);    \
    }
#define MFMA12(mh_, nh_, BF)                                                   \
    _Pragma("unroll")                                                          \
    for (int mf = 0; mf < 2; ++mf)                                             \
        _Pragma("unroll")                                                      \
        for (int nf = 0; nf < 3; ++nf) {                                       \
            acc[(mh_)*2+mf][(nh_)*3+nf] = __builtin_amdgcn_mfma_f32_16x16x32_bf16( \
                af[mf][0], BF[nf][0], acc[(mh_)*2+mf][(nh_)*3+nf], 0,0,0);     \
            acc[(mh_)*2+mf][(nh_)*3+nf] = __builtin_amdgcn_mfma_f32_16x16x32_bf16( \
                af[mf][1], BF[nf][1], acc[(mh_)*2+mf][(nh_)*3+nf], 0,0,0);     \
        }
#define BARR()  __builtin_amdgcn_s_barrier()
#define SCB0()  __builtin_amdgcn_sched_barrier(0)
#define LGKM()  asm volatile("s_waitcnt lgkmcnt(0)" ::: "memory")
#define PRIO1() __builtin_amdgcn_s_setprio(1)
#define PRIO0() __builtin_amdgcn_s_setprio(0)

    #pragma unroll 1
    for (int i = 0; i < 8; ++i) {                         // iter = K-tiles 2i, 2i+1
        const int kk1 = i*128 + 64, kk2 = i*128 + 128, kk3 = i*128 + 192;
        const bool pf = (i < 7);

        // -------- P1: b0 (mh0,nh0); reads 10; stage A-mh1'(T+1), B-nh1'u0 --------
        LDA(0,0); LDB(0,0,bf0);
        SA(1,1,kk1); SB(1,0,1,kk1);
        BARR(); LGKM(); SCB0();
        PRIO1(); MFMA12(0,0,bf0); PRIO0();
        SCB0(); BARR();

        // -------- P2: b0 (mh0,nh1); reads 6; stage B-nh1'u1,u2(T+1) --------
        LDB(1,0,bf1);
        SB(1,1,1,kk1); SB(1,2,1,kk1);
        BARR(); LGKM(); SCB0();
        PRIO1(); MFMA12(0,1,bf1); PRIO0();
        SCB0(); BARR();

        // -------- P3: b0 (mh1,nh0); reads 4; stage A-mh0(T+2), B-nh0 u0 --------
        LDA(1,0);
        if (pf) { SA(0,0,kk2); SB(0,0,0,kk2); }
        BARR(); LGKM(); SCB0();
        PRIO1(); MFMA12(1,0,bf0); PRIO0();
        SCB0(); BARR();

        // -------- P4: b0 (mh1,nh1); reads 0; stage B-nh0 u1,u2(T+2); vmcnt --------
        if (pf) { SB(0,1,0,kk2); SB(0,2,0,kk2); }
        BARR(); SCB0();
        PRIO1(); MFMA12(1,1,bf1); PRIO0();
        SCB0();
        if (pf) { asm volatile("s_waitcnt vmcnt(4)" ::: "memory"); }
        else    { asm volatile("s_waitcnt vmcnt(0)" ::: "memory"); }
        BARR();

        // -------- P5: b1 (mh0,nh0); reads 10; stage A-mh1(T+2), B-nh1 u0 --------
        LDA(0,1); LDB(0,1,bf0);
        if (pf) { SA(1,0,kk2); SB(1,0,0,kk2); }
        BARR(); LGKM(); SCB0();
        PRIO1(); MFMA12(0,0,bf0); PRIO0();
        SCB0(); BARR();

        // -------- P6: b1 (mh0,nh1); reads 6; stage B-nh1 u1,u2(T+2) --------
        LDB(1,1,bf1);
        if (pf) { SB(1,1,0,kk2); SB(1,2,0,kk2); }
        BARR(); LGKM(); SCB0();
        PRIO1(); MFMA12(0,1,bf1); PRIO0();
        SCB0(); BARR();

        // -------- P7: b1 (mh1,nh0); reads 4; stage A-mh0'(T+3), B-nh0'u0 --------
        LDA(1,1);
        if (pf) { SA(0,1,kk3); SB(0,0,1,kk3); }
        BARR(); LGKM(); SCB0();
        PRIO1(); MFMA12(1,0,bf0); PRIO0();
        SCB0(); BARR();

        // -------- P8: b1 (mh1,nh1); reads 0; stage B-nh0'u1,u2(T+3); vmcnt --------
        if (pf) { SB(0,1,1,kk3); SB(0,2,1,kk3); }
        BARR(); SCB0();
        PRIO1(); MFMA12(1,1,bf1); PRIO0();
        SCB0();
        if (pf) { asm volatile("s_waitcnt vmcnt(4)" ::: "memory"); BARR(); }
    }

#undef SA
#undef SB
#undef LDA
#undef LDB
#undef MFMA12

    // ---- epilogue: C/D 16x16 layout col = ln, row = l4*4 + r ----
    #pragma unroll
    for (int mh = 0; mh < 2; ++mh)
      #pragma unroll
      for (int mf = 0; mf < 2; ++mf)
        #pragma unroll
        for (int nh = 0; nh < 2; ++nh)
          #pragma unroll
          for (int nf = 0; nf < 3; ++nf) {
              const f32x4 a4 = acc[mh*2+mf][nh*3+nf];
              int rowg = m0 + wm*64 + mh*32 + mf*16 + l4*4;   // token (+r)
              int colg = n0 + wn*96 + nh*48 + nf*16 + ln;     // global out dim
              if (colg < 2048) {                               // Q or K, row-major
                  uint16_t* C = C0 + (size_t)(colg >> 10) * 8388608;
                  int col = colg & 1023;
                  #pragma unroll
                  for (int r = 0; r < 4; ++r)
                      C[(size_t)(rowg + r)*1024 + col] = f2bf(a4[r]);
              } else {                                         // V, transposed
                  int dg = colg - 2048;
                  int bb = rowg >> 11, nn = rowg & 2047;
                  ushort4 o4;
                  o4.x = f2bf(a4[0]); o4.y = f2bf(a4[1]);
                  o4.z = f2bf(a4[2]); o4.w = f2bf(a4[3]);
                  *(ushort4*)(vtb + ((size_t)(bb*1024 + dg))*Nseq + nn) = o4;
              }
          }
}

// ---------------------------------------------------------------------------
// GEMM  C[m][n] = sum_k A[m][k] * W[n][k]   (B^T layout, both row-major over K)
// 128x128 tile, BK=64, 256 thr = 4 waves (2x2) -- retained for the output
// projection (N=1024; 512 blocks).
// ---------------------------------------------------------------------------
template <typename OutT>
__global__ __launch_bounds__(256) void gemm_bt(
    const uint16_t* __restrict__ A, const uint16_t* __restrict__ W0,
    OutT* __restrict__ C0, int K, int Nld, int blocksPerSec,
    size_t wSecStride, size_t cSecStride, uint16_t* __restrict__ vtb, int vSec)
{
    __shared__ __align__(16) uint16_t As[128*64];
    __shared__ __align__(16) uint16_t Bs[128*64];

    const int t = threadIdx.x, lane = t & 63, w = t >> 6;
    const int wr = w >> 1, wc = w & 1;
    const int half = lane >> 5, ml = lane & 31;

    const int m0  = blockIdx.x * 128;
    const int sec = blockIdx.y / blocksPerSec;
    const int n0  = (blockIdx.y % blocksPerSec) * 128;
    const uint16_t* Wp = W0 + (size_t)sec * wSecStride;
    OutT* C = C0 + (size_t)sec * cSecStride;

    int srow[4], sg[4];
    #pragma unroll
    for (int i = 0; i < 4; ++i) {
        int s = t + 256*i;
        srow[i] = s >> 3;
        sg[i]   = (s & 7) ^ (srow[i] & 7);
    }

    int arow[2], brow[2];
    #pragma unroll
    for (int i = 0; i < 2; ++i) {
        arow[i] = wr*64 + i*32 + ml;
        brow[i] = wc*64 + i*32 + ml;
    }

    f32x16 acc[2][2] = {};

    for (int k0 = 0; k0 < K; k0 += 64) {
        __syncthreads();
        #pragma unroll
        for (int i = 0; i < 4; ++i) {
            asyncLoad16(A  + (size_t)(m0 + srow[i])*K + k0 + sg[i]*8,
                        As + (size_t)(w*64 + 256*i)*8);
            asyncLoad16(Wp + (size_t)(n0 + srow[i])*K + k0 + sg[i]*8,
                        Bs + (size_t)(w*64 + 256*i)*8);
        }
        __syncthreads();

        #pragma unroll
        for (int s = 0; s < 4; ++s) {            // k-step of 16
            const int chunk = s*2 + half;
            bf16x8 af[2], bfr[2];
            #pragma unroll
            for (int i = 0; i < 2; ++i) {
                int m = arow[i];
                af[i]  = *(const bf16x8*)(As + (size_t)(m*8 + (chunk ^ (m & 7)))*8);
                int n = brow[i];
                bfr[i] = *(const bf16x8*)(Bs + (size_t)(n*8 + (chunk ^ (n & 7)))*8);
            }
            #pragma unroll
            for (int mt = 0; mt < 2; ++mt)
                #pragma unroll
                for (int nt = 0; nt < 2; ++nt)
                    acc[mt][nt] = __builtin_amdgcn_mfma_f32_32x32x16_bf16(
                        af[mt], bfr[nt], acc[mt][nt], 0, 0, 0);
        }
    }

    if (vtb != nullptr && sec == vSec) {
        #pragma unroll
        for (int mt = 0; mt < 2; ++mt)
            #pragma unroll
            for (int nt = 0; nt < 2; ++nt) {
                int colg = n0 + wc*64 + nt*32 + ml;               // dim
                int hh = colg >> 6, dd = colg & 63;
                #pragma unroll
                for (int g = 0; g < 4; ++g) {
                    int rowg = m0 + wr*64 + mt*32 + 8*g + 4*half; // token (+reg&3)
                    int bb = rowg >> 11, nn = rowg & 2047;
                    ushort4 o4;
                    o4.x = f2bf(acc[mt][nt][4*g + 0]);
                    o4.y = f2bf(acc[mt][nt][4*g + 1]);
                    o4.z = f2bf(acc[mt][nt][4*g + 2]);
                    o4.w = f2bf(acc[mt][nt][4*g + 3]);
                    *(ushort4*)(vtb + ((size_t)((bb*NH + hh)*HD + dd))*Nseq + nn) = o4;
                }
            }
    } else {
        #pragma unroll
        for (int mt = 0; mt < 2; ++mt)
            #pragma unroll
            for (int nt = 0; nt < 2; ++nt) {
                int col = n0 + wc*64 + nt*32 + ml;
                #pragma unroll
                for (int r = 0; r < 16; ++r) {
                    int row = m0 + wr*64 + mt*32 + (r & 3) + 8*(r >> 2) + 4*half;
                    storeOut(&C[(size_t)row * Nld + col], acc[mt][nt][r]);
                }
            }
    }
}

// ---------------------------------------------------------------------------
// Flash attention, causal, no-max online softmax, S^T formulation (R4 version:
// best measured attn ~67.7us). Triple-buffered K/V staging + counted-vmcnt raw
// barriers; PV on mfma_16x16x16bf16_1k (register P^T, no LDS round-trip).
// ---------------------------------------------------------------------------
__global__ __launch_bounds__(256, 3) void attn(
    const uint16_t* __restrict__ Q, const uint16_t* __restrict__ K,
    const uint16_t* __restrict__ Vt, uint16_t* __restrict__ O)
{
    __shared__ __align__(16) uint16_t Kb[3][64*64];   // 24 KB (first 16 KB = Q scratch)
    __shared__ __align__(16) uint16_t Vb[3][64*64];   // 24 KB (V^T tiles, rows=d)

    const int t = threadIdx.x, lane = t & 63, w = t >> 6;
    const int quad = lane >> 4, c = lane & 15;
    const int y = blockIdx.y;
    const int qi = (y < 4) ? (15 - y) : (y < 8) ? (y + 4) : (y < 12) ? (y - 4) : (15 - y);
    const int q0 = qi * 128;
    const int bh = blockIdx.x, b = bh >> 4, h = bh & 15;
    const size_t tokBase = (size_t)b * Nseq;
    const int hcol = h * HD;
    uint16_t* Qs = (uint16_t*)Kb;                    // 16 KB scratch (Kb[0..1])

    #define STAGE_KV(k0_, buf_)                                             \
        _Pragma("unroll")                                                    \
        for (int i = 0; i < 2; ++i) {                                        \
            int s = t + 256*i;                                               \
            int row = s >> 3, gg = (s & 7) ^ (row & 7);                      \
            asyncLoad16(K + (tokBase + (k0_) + row)*DIMD + hcol + gg*8,      \
                        Kb[buf_] + (size_t)(w*64 + 256*i)*8);                \
            asyncLoad16(Vt + ((size_t)bh*HD + row)*Nseq + (k0_) + gg*8,      \
                        Vb[buf_] + (size_t)(w*64 + 256*i)*8);                \
        }

    // ---- stage Q (128x64) through scratch, grab fragments, then free it ----
    #pragma unroll
    for (int i = 0; i < 4; ++i) {
        int s = t + 256*i;
        int row = s >> 3, gg = (s & 7) ^ (row & 7);
        asyncLoad16(Q + (tokBase + q0 + row)*DIMD + hcol + gg*8,
                    Qs + (size_t)(w*64 + 256*i)*8);
    }
    __syncthreads();                                  // Q landed
    bf16x8 qf[2][2];
    #pragma unroll
    for (int qt = 0; qt < 2; ++qt)
        #pragma unroll
        for (int ks = 0; ks < 2; ++ks) {
            int row = w*32 + qt*16 + c;
            int pos = (ks*4 + quad) ^ (row & 7);
            qf[qt][ks] = *(const bf16x8*)(Qs + (size_t)(row*8 + pos)*8);
        }
    __syncthreads();                                  // all reads done, scratch free

    const int wrow0 = q0 + w*32;
    const int end = 2*qi + 2;                         // always >= 2
    STAGE_KV(0, 0);                                   // tiles 0 and 1 in flight
    STAGE_KV(64, 1);

    f32x4  o[2][4] = {};
    float  l_lane[2] = {0.f, 0.f};
    int b0 = 0, b1 = 1, b2 = 2;                       // cur / next / stage-target

    for (int kt = 0; kt < end; ++kt) {
        const int k0 = kt * 64;

        // buf[b0] (tile kt, staged 2 iters ago) must be ready; tile kt+1's
        // 4 loads stay in flight across the barrier.
        if (kt + 1 < end) { asm volatile("s_waitcnt vmcnt(4)\n\ts_barrier" ::: "memory"); }
        else              { asm volatile("s_waitcnt vmcnt(0)\n\ts_barrier" ::: "memory"); }

        if (kt + 2 < end) { STAGE_KV((kt+2)*64, b2); }

        if (k0 <= wrow0 + 31) {                       // wave not fully above diag
            const uint16_t* Ks = Kb[b0];
            const uint16_t* Vs = Vb[b0];

            // ---- S^T = K.Q^T : C-layout row = kv (quad*4+r), col = q (c) ----
            f32x4 sv[2][4] = {};
            __builtin_amdgcn_s_setprio(1);
            #pragma unroll
            for (int nt = 0; nt < 4; ++nt)
                #pragma unroll
                for (int ks = 0; ks < 2; ++ks) {
                    int row = nt*16 + c;
                    int pos = (ks*4 + quad) ^ (row & 7);
                    bf16x8 kf = *(const bf16x8*)(Ks + (size_t)(row*8 + pos)*8);
                    sv[0][nt] = __builtin_amdgcn_mfma_f32_16x16x32_bf16(kf, qf[0][ks], sv[0][nt], 0, 0, 0);
                    sv[1][nt] = __builtin_amdgcn_mfma_f32_16x16x32_bf16(kf, qf[1][ks], sv[1][nt], 0, 0, 0);
                }
            __builtin_amdgcn_s_setprio(0);

            // ---- causal mask (diagonal tiles only; kv > q -> -inf) ----
            if (k0 + 63 > wrow0) {
                #pragma unroll
                for (int qt = 0; qt < 2; ++qt)
                    #pragma unroll
                    for (int nt = 0; nt < 4; ++nt)
                        #pragma unroll
                        for (int r = 0; r < 4; ++r) {
                            int kvg = k0 + nt*16 + quad*4 + r;
                            int qg  = wrow0 + qt*16 + c;
                            if (kvg > qg) sv[qt][nt][r] = -340.0f;
                        }
            }

            // ---- p = exp2(s); row-sum per lane; pack P^T as B-frags ----
            s16x4 pb[2][4];
            #pragma unroll
            for (int qt = 0; qt < 2; ++qt)
                #pragma unroll
                for (int nt = 0; nt < 4; ++nt) {
                    float p0 = __builtin_amdgcn_exp2f(sv[qt][nt][0]);
                    float p1 = __builtin_amdgcn_exp2f(sv[qt][nt][1]);
                    float p2 = __builtin_amdgcn_exp2f(sv[qt][nt][2]);
                    float p3 = __builtin_amdgcn_exp2f(sv[qt][nt][3]);
                    l_lane[qt] += (p0 + p1) + (p2 + p3);
                    union { uint32_t u[2]; s16x4 v; } pu;
                    pu.u[0] = pk2(p0, p1);
                    pu.u[1] = pk2(p2, p3);
                    pb[qt][nt] = pu.v;
                }

            // ---- O^T += V^T.P^T  (K=16 steps; A=V^T rows from LDS b64) ----
            __builtin_amdgcn_s_setprio(1);
            #pragma unroll
            for (int s4 = 0; s4 < 4; ++s4)
                #pragma unroll
                for (int dt = 0; dt < 4; ++dt) {
                    int row = dt*16 + c;                    // d
                    int chunk = s4*2 + (quad >> 1);
                    int pos = chunk ^ (row & 7);
                    s16x4 vf = *(const s16x4*)(Vs + (size_t)(row*8 + pos)*8 + (quad & 1)*4);
                    o[0][dt] = __builtin_amdgcn_mfma_f32_16x16x16bf16_1k(vf, pb[0][s4], o[0][dt], 0, 0, 0);
                    o[1][dt] = __builtin_amdgcn_mfma_f32_16x16x16bf16_1k(vf, pb[1][s4], o[1][dt], 0, 0, 0);
                }
            __builtin_amdgcn_s_setprio(0);
        }

        int tmp = b0; b0 = b1; b1 = b2; b2 = tmp;     // rotate buffers
    }

    // ---- epilogue: reduce l over quads, scale, store O^T packed ----
    #pragma unroll
    for (int qt = 0; qt < 2; ++qt) {
        float l = l_lane[qt];
        l += __shfl_xor(l, 16);
        l += __shfl_xor(l, 32);
        float inv = 1.0f / l;
        int tok = (int)(q0 + w*32 + qt*16 + c);
        #pragma unroll
        for (int dt = 0; dt < 4; ++dt) {
            ushort4 o4;
            o4.x = f2bf(o[qt][dt][0] * inv);
            o4.y = f2bf(o[qt][dt][1] * inv);
            o4.z = f2bf(o[qt][dt][2] * inv);
            o4.w = f2bf(o[qt][dt][3] * inv);
            *(ushort4*)(O + (tokBase + tok)*DIMD + hcol + dt*16 + quad*4) = o4;
        }
    }
    #undef STAGE_KV
}

// ---------------------------------------------------------------------------
extern "C" void kernel_launch(void* const* d_in, const int* in_sizes, int n_in,
                              void* d_out, int out_size, void* d_ws, size_t ws_size,
                              hipStream_t stream) {
    const float* x  = (const float*)d_in[0];
    // d_in[1] = causal tril mask, deterministic -> handled analytically
    const float* Wq = (const float*)d_in[2];
    const float* Wk = (const float*)d_in[3];
    const float* Wv = (const float*)d_in[4];
    const float* Wo = (const float*)d_in[5];

    uint16_t* ws  = (uint16_t*)d_ws;
    uint16_t* xb  = ws;                      // x bf16 (later reused as attn out)
    uint16_t* wqb = ws + 8388608;            // Wq,Wk,Wv,Wo bf16 contiguous
    uint16_t* wob = wqb + 3*1048576;
    uint16_t* qb  = ws + 12582912;           // Q
    uint16_t* kb  = qb + 8388608;            // K
    uint16_t* vtb = kb + 8388608;            // V transposed per (b,h)
    uint16_t* ab  = xb;                      // attention output reuses xb

    cast_all<<<12288, 256, 0, stream>>>(x, Wq, Wk, Wv, Wo, ws);

    // QKV: 128x384 8-phase counted-vmcnt kernel; 512 blocks = 2 exact rounds.
    gemm_qkv384<<<dim3(64, 8), 512, 0, stream>>>(xb, wqb, qb, vtb);

    attn<<<dim3(64, 16), 256, 0, stream>>>(qb, kb, vtb, ab);

    gemm_bt<float><<<dim3(64, 8), 256, 0, stream>>>(
        ab, wob, (float*)d_out, DIMD, DIMD, 8, (size_t)0, (size_t)0, nullptr, -1);
}

// Round 9
// 242.814 us; speedup vs baseline: 1.5247x; 1.0199x over previous
//
#include <hip/hip_runtime.h>
#include <stdint.h>

#define Bq   4
#define Nseq 2048
#define NH   16
#define HD   64
#define DIMD 1024

typedef float  f32x4   __attribute__((ext_vector_type(4)));
typedef float  f32x16  __attribute__((ext_vector_type(16)));
typedef __bf16 bf16x8  __attribute__((ext_vector_type(8)));
typedef short  s16x4   __attribute__((ext_vector_type(4)));

typedef __attribute__((address_space(1))) void as1_void;
typedef __attribute__((address_space(3))) void as3_void;

static __device__ __forceinline__ uint16_t f2bf(float f) {
    uint32_t u = __builtin_bit_cast(uint32_t, f);
    u += 0x7fffu + ((u >> 16) & 1u);          // RNE
    return (uint16_t)(u >> 16);
}

// truncation-pack two fp32 -> packed bf16x2 (p>=0, 1-ulp bias, cancels in p/l)
static __device__ __forceinline__ uint32_t pk2(float a, float b) {
    uint32_t ua = __builtin_bit_cast(uint32_t, a);
    uint32_t ub = __builtin_bit_cast(uint32_t, b);
    return (ua >> 16) | (ub & 0xffff0000u);
}

static __device__ __forceinline__ void asyncLoad16(const uint16_t* g, uint16_t* l) {
    __builtin_amdgcn_global_load_lds((as1_void*)g, (as3_void*)l, 16, 0, 0);
}

// ---------------------------------------------------------------------------
// cast fp32 -> bf16 : x (8388608) then Wq,Wk,Wv,Wo (4 x 1048576), dst contiguous
// Wq is pre-scaled by SCALE*log2(e) so attention can use exp2 on raw QK dots.
// ---------------------------------------------------------------------------
__global__ void cast_all(const float* __restrict__ x,
                         const float* __restrict__ wq, const float* __restrict__ wk,
                         const float* __restrict__ wv, const float* __restrict__ wo,
                         uint16_t* __restrict__ dst) {
    size_t i = ((size_t)blockIdx.x * blockDim.x + threadIdx.x) * 4;  // elem idx
    const float* src; size_t off; float scale = 1.0f;
    if (i < 8388608) { src = x; off = i; }
    else {
        size_t wI = i - 8388608;
        size_t wi = wI >> 20;
        off = wI & 1048575;
        src = (wi == 0) ? wq : (wi == 1) ? wk : (wi == 2) ? wv : wo;
        if (wi == 0) scale = 0.18033688011112042f;   // (1/sqrt(64)) * log2(e)
    }
    float4 v = *(const float4*)(src + off);
    ushort4 o;
    o.x = f2bf(v.x * scale); o.y = f2bf(v.y * scale);
    o.z = f2bf(v.z * scale); o.w = f2bf(v.w * scale);
    *(ushort4*)(dst + i) = o;
}

#define BARR()  __builtin_amdgcn_s_barrier()
#define SCB0()  __builtin_amdgcn_sched_barrier(0)
#define LGKM()  asm volatile("s_waitcnt lgkmcnt(0)" ::: "memory")
#define PRIO1() __builtin_amdgcn_s_setprio(1)
#define PRIO0() __builtin_amdgcn_s_setprio(0)

// ---------------------------------------------------------------------------
// QKV GEMM: 8-phase counted-vmcnt engine, BM=128 x BN=384 (R7, measured 65.5us,
// conflicts 0). Grid (64,8) = 512 blocks = 2 exact rounds at 1 block/CU.
// Units 8/K-tile (A 2, B 6), 2 staged per phase, vmcnt(4) at P4/P8 only;
// all fragment rows == ln mod 8 -> swizzle conflict-free.
// ---------------------------------------------------------------------------
__global__ __launch_bounds__(512, 2) void gemm_qkv384(
    const uint16_t* __restrict__ A, const uint16_t* __restrict__ W0,
    uint16_t* __restrict__ C0, uint16_t* __restrict__ vtb)
{
    __shared__ __align__(16) uint16_t Asm[2][2][4096];    // [buf][mh][64 rows x 64]
    __shared__ __align__(16) uint16_t Bsm[2][2][12288];   // [buf][nh][3 units x 64 x 64]

    const int t = threadIdx.x, lane = t & 63, w = t >> 6;
    const int wm = w >> 2, wn = w & 3;                    // 2 x 4 wave grid
    const int ln = lane & 15, l4 = lane >> 4;

    const int m0 = blockIdx.x * 128;
    const int n0 = blockIdx.y * 384;                      // global over Q|K|V rows

    const int srow = t >> 3;                              // 0..63
    const int sg   = (t & 7) ^ (srow & 7);
    const uint16_t* aBase = A + (size_t)(m0 + (srow >> 5)*64 + (srow & 31))*DIMD + sg*8;
    const uint16_t* bBase[3];
    #pragma unroll
    for (int j = 0; j < 3; ++j) {
        int f = j*64 + srow;
        int wnf = f / 48, off = f % 48;
        bBase[j] = W0 + (size_t)(n0 + wnf*96 + off)*DIMD + sg*8;
    }

#define SA(mh_, buf_, kk_) asyncLoad16(aBase + (size_t)(mh_)*32*DIMD + (kk_), \
        &Asm[buf_][mh_][t*8])
#define SB(nh_, j_, buf_, kk_) asyncLoad16(bBase[j_] + (size_t)(nh_)*48*DIMD + (kk_), \
        &Bsm[buf_][nh_][(j_)*4096 + t*8])

    SA(0,0,0); SA(1,0,0);
    SB(0,0,0,0); SB(0,1,0,0); SB(0,2,0,0);
    SB(1,0,0,0); SB(1,1,0,0); SB(1,2,0,0);
    SA(0,1,64);
    SB(0,0,1,64); SB(0,1,1,64); SB(0,2,1,64);
    asm volatile("s_waitcnt vmcnt(4)" ::: "memory");
    BARR();

    const int cs0 = ( l4      ^ (ln & 7)) * 8;
    const int cs1 = ((4 + l4) ^ (ln & 7)) * 8;
    const int awo = wm*2048 + ln*64;
    const int bwo = wn*3072 + ln*64;

    bf16x8 af[2][2], bf0[3][2], bf1[3][2];
    f32x4 acc[4][6] = {};

#define LDA(mh_, buf_)                                                         \
    _Pragma("unroll")                                                          \
    for (int mf = 0; mf < 2; ++mf) {                                           \
        af[mf][0] = *(const bf16x8*)(&Asm[buf_][mh_][awo + mf*1024 + cs0]);    \
        af[mf][1] = *(const bf16x8*)(&Asm[buf_][mh_][awo + mf*1024 + cs1]);    \
    }
#define LDB(nh_, buf_, BF)                                                     \
    _Pragma("unroll")                                                          \
    for (int nf = 0; nf < 3; ++nf) {                                           \
        BF[nf][0] = *(const bf16x8*)(&Bsm[buf_][nh_][bwo + nf*1024 + cs0]);    \
        BF[nf][1] = *(const bf16x8*)(&Bsm[buf_][nh_][bwo + nf*1024 + cs1]);    \
    }
#define MFMA12(mh_, nh_, BF)                                                   \
    _Pragma("unroll")                                                          \
    for (int mf = 0; mf < 2; ++mf)                                             \
        _Pragma("unroll")                                                      \
        for (int nf = 0; nf < 3; ++nf) {                                       \
            acc[(mh_)*2+mf][(nh_)*3+nf] = __builtin_amdgcn_mfma_f32_16x16x32_bf16( \
                af[mf][0], BF[nf][0], acc[(mh_)*2+mf][(nh_)*3+nf], 0,0,0);     \
            acc[(mh_)*2+mf][(nh_)*3+nf] = __builtin_amdgcn_mfma_f32_16x16x32_bf16( \
                af[mf][1], BF[nf][1], acc[(mh_)*2+mf][(nh_)*3+nf], 0,0,0);     \
        }

    #pragma unroll 1
    for (int i = 0; i < 8; ++i) {
        const int kk1 = i*128 + 64, kk2 = i*128 + 128, kk3 = i*128 + 192;
        const bool pf = (i < 7);

        LDA(0,0); LDB(0,0,bf0);
        SA(1,1,kk1); SB(1,0,1,kk1);
        BARR(); LGKM(); SCB0();
        PRIO1(); MFMA12(0,0,bf0); PRIO0();
        SCB0(); BARR();

        LDB(1,0,bf1);
        SB(1,1,1,kk1); SB(1,2,1,kk1);
        BARR(); LGKM(); SCB0();
        PRIO1(); MFMA12(0,1,bf1); PRIO0();
        SCB0(); BARR();

        LDA(1,0);
        if (pf) { SA(0,0,kk2); SB(0,0,0,kk2); }
        BARR(); LGKM(); SCB0();
        PRIO1(); MFMA12(1,0,bf0); PRIO0();
        SCB0(); BARR();

        if (pf) { SB(0,1,0,kk2); SB(0,2,0,kk2); }
        BARR(); SCB0();
        PRIO1(); MFMA12(1,1,bf1); PRIO0();
        SCB0();
        if (pf) { asm volatile("s_waitcnt vmcnt(4)" ::: "memory"); }
        else    { asm volatile("s_waitcnt vmcnt(0)" ::: "memory"); }
        BARR();

        LDA(0,1); LDB(0,1,bf0);
        if (pf) { SA(1,0,kk2); SB(1,0,0,kk2); }
        BARR(); LGKM(); SCB0();
        PRIO1(); MFMA12(0,0,bf0); PRIO0();
        SCB0(); BARR();

        LDB(1,1,bf1);
        if (pf) { SB(1,1,0,kk2); SB(1,2,0,kk2); }
        BARR(); LGKM(); SCB0();
        PRIO1(); MFMA12(0,1,bf1); PRIO0();
        SCB0(); BARR();

        LDA(1,1);
        if (pf) { SA(0,1,kk3); SB(0,0,1,kk3); }
        BARR(); LGKM(); SCB0();
        PRIO1(); MFMA12(1,0,bf0); PRIO0();
        SCB0(); BARR();

        if (pf) { SB(0,1,1,kk3); SB(0,2,1,kk3); }
        BARR(); SCB0();
        PRIO1(); MFMA12(1,1,bf1); PRIO0();
        SCB0();
        if (pf) { asm volatile("s_waitcnt vmcnt(4)" ::: "memory"); BARR(); }
    }

#undef SA
#undef SB
#undef LDA
#undef LDB
#undef MFMA12

    // ---- epilogue: C/D 16x16 layout col = ln, row = l4*4 + r ----
    #pragma unroll
    for (int mh = 0; mh < 2; ++mh)
      #pragma unroll
      for (int mf = 0; mf < 2; ++mf)
        #pragma unroll
        for (int nh = 0; nh < 2; ++nh)
          #pragma unroll
          for (int nf = 0; nf < 3; ++nf) {
              const f32x4 a4 = acc[mh*2+mf][nh*3+nf];
              int rowg = m0 + wm*64 + mh*32 + mf*16 + l4*4;   // token (+r)
              int colg = n0 + wn*96 + nh*48 + nf*16 + ln;     // global out dim
              if (colg < 2048) {                               // Q or K, row-major
                  uint16_t* C = C0 + (size_t)(colg >> 10) * 8388608;
                  int col = colg & 1023;
                  #pragma unroll
                  for (int r = 0; r < 4; ++r)
                      C[(size_t)(rowg + r)*1024 + col] = f2bf(a4[r]);
              } else {                                         // V, transposed
                  int dg = colg - 2048;
                  int bb = rowg >> 11, nn = rowg & 2047;
                  ushort4 o4;
                  o4.x = f2bf(a4[0]); o4.y = f2bf(a4[1]);
                  o4.z = f2bf(a4[2]); o4.w = f2bf(a4[3]);
                  *(ushort4*)(vtb + ((size_t)(bb*1024 + dg))*Nseq + nn) = o4;
              }
          }
}

// ---------------------------------------------------------------------------
// Output projection: same 8-phase engine, BM=256 x BN=128 -> grid (32,8) =
// 256 blocks = EXACTLY ONE round at 1 block/CU (96 KiB LDS): zero tail.
// 8 waves 2Mx4N; per-wave 128x32 = 8mf x 2nf; phase = (mh: 4mf)x(nh: 1nf)
// x 2ks = 8 MFMA. Reads 10/2/8/0.  Units/K-tile: A 4 (mh-pure), B 2 (nh-pure).
// Stage plan: P1: A-mh1(k+1)->other; P3: B(k+2)+A-mh0(k+2)->own; vmcnt(4)@P4/P8.
// FIFO induction & liveness audited (see R7/R8 notes); barriers block-uniform.
// ---------------------------------------------------------------------------
__global__ __launch_bounds__(512, 2) void gemm_out256(
    const uint16_t* __restrict__ A, const uint16_t* __restrict__ W0,
    float* __restrict__ C)
{
    __shared__ __align__(16) uint16_t Asm[2][2][8192];    // [buf][mh][2 units x 64 x 64]
    __shared__ __align__(16) uint16_t Bsm[2][2][4096];    // [buf][nh][64 rows x 64]

    const int t = threadIdx.x, lane = t & 63, w = t >> 6;
    const int wm = w >> 2, wn = w & 3;                    // 2 x 4 wave grid
    const int ln = lane & 15, l4 = lane >> 4;

    const int m0 = blockIdx.x * 256;
    const int n0 = blockIdx.y * 128;

    const int srow = t >> 3;                              // 0..63
    const int sg   = (t & 7) ^ (srow & 7);
    const uint16_t* aBase = A + (size_t)(m0 + srow)*DIMD + sg*8;
    const uint16_t* bBase = W0 + (size_t)(n0 + (srow >> 4)*32 + (srow & 15))*DIMD + sg*8;

#define SA(mh_, j_, buf_, kk_) asyncLoad16(aBase + (size_t)((j_)*128 + (mh_)*64)*DIMD + (kk_), \
        &Asm[buf_][mh_][(j_)*4096 + t*8])
#define SB(nh_, buf_, kk_) asyncLoad16(bBase + (size_t)(nh_)*16*DIMD + (kk_), \
        &Bsm[buf_][nh_][t*8])

    // prologue: tile0 = B(0), A-mh0(0), A-mh1(0); then B(1), A-mh0(1)
    SB(0,0,0); SB(1,0,0);
    SA(0,0,0,0); SA(0,1,0,0);
    SA(1,0,0,0); SA(1,1,0,0);
    SB(0,1,64); SB(1,1,64);
    SA(0,0,1,64); SA(0,1,1,64);
    asm volatile("s_waitcnt vmcnt(4)" ::: "memory");
    BARR();

    const int cs0 = ( l4      ^ (ln & 7)) * 8;
    const int cs1 = ((4 + l4) ^ (ln & 7)) * 8;
    const int awo = wm*4096 + ln*64;                      // + mf*1024 + cs
    const int bwo = wn*1024 + ln*64;                      // + cs

    bf16x8 af[4][2], bfA[2], bfB[2];
    f32x4 acc[8][2] = {};

#define LDA(mh_, buf_)                                                         \
    _Pragma("unroll")                                                          \
    for (int mf = 0; mf < 4; ++mf) {                                           \
        af[mf][0] = *(const bf16x8*)(&Asm[buf_][mh_][awo + mf*1024 + cs0]);    \
        af[mf][1] = *(const bf16x8*)(&Asm[buf_][mh_][awo + mf*1024 + cs1]);    \
    }
#define LDB(nh_, buf_, BF)                                                     \
    BF[0] = *(const bf16x8*)(&Bsm[buf_][nh_][bwo + cs0]);                      \
    BF[1] = *(const bf16x8*)(&Bsm[buf_][nh_][bwo + cs1]);
#define MFMA8(mh_, nh_, BF)                                                    \
    _Pragma("unroll")                                                          \
    for (int mf = 0; mf < 4; ++mf) {                                           \
        acc[(mh_)*4+mf][nh_] = __builtin_amdgcn_mfma_f32_16x16x32_bf16(        \
            af[mf][0], BF[0], acc[(mh_)*4+mf][nh_], 0,0,0);                    \
        acc[(mh_)*4+mf][nh_] = __builtin_amdgcn_mfma_f32_16x16x32_bf16(        \
            af[mf][1], BF[1], acc[(mh_)*4+mf][nh_], 0,0,0);                    \
    }

    #pragma unroll 1
    for (int i = 0; i < 8; ++i) {                         // tiles 2i (b0), 2i+1 (b1)
        const int kk1 = i*128 + 64, kk2 = i*128 + 128, kk3 = i*128 + 192;
        const bool pf2 = (i < 7);                         // tile 2i+2 exists
        const bool pf3 = (i < 7);                         // tile 2i+3 exists

        // -------- P1: b0 (mh0,nh0); reads 10; stage A-mh1(2i+1)->b1 --------
        LDA(0,0); LDB(0,0,bfA);
        SA(1,0,1,kk1); SA(1,1,1,kk1);
        BARR(); LGKM(); SCB0();
        PRIO1(); MFMA8(0,0,bfA); PRIO0();
        SCB0(); BARR();

        // -------- P2: b0 (mh0,nh1); reads 2 --------
        LDB(1,0,bfB);
        BARR(); LGKM(); SCB0();
        PRIO1(); MFMA8(0,1,bfB); PRIO0();
        SCB0(); BARR();

        // -------- P3: b0 (mh1,nh0); reads 8; stage B(2i+2), A-mh0(2i+2)->b0 --------
        LDA(1,0);
        if (pf2) { SB(0,0,kk2); SB(1,0,kk2); SA(0,0,0,kk2); SA(0,1,0,kk2); }
        BARR(); LGKM(); SCB0();
        PRIO1(); MFMA8(1,0,bfA); PRIO0();
        SCB0(); BARR();

        // -------- P4: b0 (mh1,nh1); reads 0; vmcnt forces tile 2i+1 --------
        BARR(); SCB0();
        PRIO1(); MFMA8(1,1,bfB); PRIO0();
        SCB0();
        if (pf2) { asm volatile("s_waitcnt vmcnt(4)" ::: "memory"); }
        else     { asm volatile("s_waitcnt vmcnt(0)" ::: "memory"); }
        BARR();

        // -------- P5: b1 (mh0,nh0); reads 10; stage A-mh1(2i+2)->b0 --------
        LDA(0,1); LDB(0,1,bfA);
        if (pf2) { SA(1,0,0,kk2); SA(1,1,0,kk2); }
        BARR(); LGKM(); SCB0();
        PRIO1(); MFMA8(0,0,bfA); PRIO0();
        SCB0(); BARR();

        // -------- P6: b1 (mh0,nh1); reads 2 --------
        LDB(1,1,bfB);
        BARR(); LGKM(); SCB0();
        PRIO1(); MFMA8(0,1,bfB); PRIO0();
        SCB0(); BARR();

        // -------- P7: b1 (mh1,nh0); reads 8; stage B(2i+3), A-mh0(2i+3)->b1 --------
        LDA(1,1);
        if (pf3) { SB(0,1,kk3); SB(1,1,kk3); SA(0,0,1,kk3); SA(0,1,1,kk3); }
        BARR(); LGKM(); SCB0();
        PRIO1(); MFMA8(1,0,bfA); PRIO0();
        SCB0(); BARR();

        // -------- P8: b1 (mh1,nh1); reads 0; vmcnt forces tile 2i+2 --------
        BARR(); SCB0();
        PRIO1(); MFMA8(1,1,bfB); PRIO0();
        SCB0();
        if (pf3) { asm volatile("s_waitcnt vmcnt(4)" ::: "memory"); BARR(); }
    }

#undef SA
#undef SB
#undef LDA
#undef LDB
#undef MFMA8

    // ---- epilogue: C/D 16x16 layout col = ln, row = l4*4 + r; fp32 out ----
    #pragma unroll
    for (int mh = 0; mh < 2; ++mh)
      #pragma unroll
      for (int mf = 0; mf < 4; ++mf)
        #pragma unroll
        for (int nh = 0; nh < 2; ++nh) {
            const f32x4 a4 = acc[mh*4+mf][nh];
            int rowg = m0 + wm*128 + mh*64 + mf*16 + l4*4;
            int colg = n0 + wn*32 + nh*16 + ln;
            #pragma unroll
            for (int r = 0; r < 4; ++r)
                C[(size_t)(rowg + r)*1024 + colg] = a4[r];
        }
}

// ---------------------------------------------------------------------------
// Flash attention, causal, no-max online softmax, S^T formulation (R4 version:
// best measured attn ~67.7us). Triple-buffered K/V staging + counted-vmcnt raw
// barriers; PV on mfma_16x16x16bf16_1k (register P^T, no LDS round-trip).
// ---------------------------------------------------------------------------
__global__ __launch_bounds__(256, 3) void attn(
    const uint16_t* __restrict__ Q, const uint16_t* __restrict__ K,
    const uint16_t* __restrict__ Vt, uint16_t* __restrict__ O)
{
    __shared__ __align__(16) uint16_t Kb[3][64*64];   // 24 KB (first 16 KB = Q scratch)
    __shared__ __align__(16) uint16_t Vb[3][64*64];   // 24 KB (V^T tiles, rows=d)

    const int t = threadIdx.x, lane = t & 63, w = t >> 6;
    const int quad = lane >> 4, c = lane & 15;
    const int y = blockIdx.y;
    const int qi = (y < 4) ? (15 - y) : (y < 8) ? (y + 4) : (y < 12) ? (y - 4) : (15 - y);
    const int q0 = qi * 128;
    const int bh = blockIdx.x, b = bh >> 4, h = bh & 15;
    const size_t tokBase = (size_t)b * Nseq;
    const int hcol = h * HD;
    uint16_t* Qs = (uint16_t*)Kb;                    // 16 KB scratch (Kb[0..1])

    #define STAGE_KV(k0_, buf_)                                             \
        _Pragma("unroll")                                                    \
        for (int i = 0; i < 2; ++i) {                                        \
            int s = t + 256*i;                                               \
            int row = s >> 3, gg = (s & 7) ^ (row & 7);                      \
            asyncLoad16(K + (tokBase + (k0_) + row)*DIMD + hcol + gg*8,      \
                        Kb[buf_] + (size_t)(w*64 + 256*i)*8);                \
            asyncLoad16(Vt + ((size_t)bh*HD + row)*Nseq + (k0_) + gg*8,      \
                        Vb[buf_] + (size_t)(w*64 + 256*i)*8);                \
        }

    // ---- stage Q (128x64) through scratch, grab fragments, then free it ----
    #pragma unroll
    for (int i = 0; i < 4; ++i) {
        int s = t + 256*i;
        int row = s >> 3, gg = (s & 7) ^ (row & 7);
        asyncLoad16(Q + (tokBase + q0 + row)*DIMD + hcol + gg*8,
                    Qs + (size_t)(w*64 + 256*i)*8);
    }
    __syncthreads();                                  // Q landed
    bf16x8 qf[2][2];
    #pragma unroll
    for (int qt = 0; qt < 2; ++qt)
        #pragma unroll
        for (int ks = 0; ks < 2; ++ks) {
            int row = w*32 + qt*16 + c;
            int pos = (ks*4 + quad) ^ (row & 7);
            qf[qt][ks] = *(const bf16x8*)(Qs + (size_t)(row*8 + pos)*8);
        }
    __syncthreads();                                  // all reads done, scratch free

    const int wrow0 = q0 + w*32;
    const int end = 2*qi + 2;                         // always >= 2
    STAGE_KV(0, 0);                                   // tiles 0 and 1 in flight
    STAGE_KV(64, 1);

    f32x4  o[2][4] = {};
    float  l_lane[2] = {0.f, 0.f};
    int b0 = 0, b1 = 1, b2 = 2;                       // cur / next / stage-target

    for (int kt = 0; kt < end; ++kt) {
        const int k0 = kt * 64;

        if (kt + 1 < end) { asm volatile("s_waitcnt vmcnt(4)\n\ts_barrier" ::: "memory"); }
        else              { asm volatile("s_waitcnt vmcnt(0)\n\ts_barrier" ::: "memory"); }

        if (kt + 2 < end) { STAGE_KV((kt+2)*64, b2); }

        if (k0 <= wrow0 + 31) {                       // wave not fully above diag
            const uint16_t* Ks = Kb[b0];
            const uint16_t* Vs = Vb[b0];

            // ---- S^T = K.Q^T : C-layout row = kv (quad*4+r), col = q (c) ----
            f32x4 sv[2][4] = {};
            __builtin_amdgcn_s_setprio(1);
            #pragma unroll
            for (int nt = 0; nt < 4; ++nt)
                #pragma unroll
                for (int ks = 0; ks < 2; ++ks) {
                    int row = nt*16 + c;
                    int pos = (ks*4 + quad) ^ (row & 7);
                    bf16x8 kf = *(const bf16x8*)(Ks + (size_t)(row*8 + pos)*8);
                    sv[0][nt] = __builtin_amdgcn_mfma_f32_16x16x32_bf16(kf, qf[0][ks], sv[0][nt], 0, 0, 0);
                    sv[1][nt] = __builtin_amdgcn_mfma_f32_16x16x32_bf16(kf, qf[1][ks], sv[1][nt], 0, 0, 0);
                }
            __builtin_amdgcn_s_setprio(0);

            // ---- causal mask (diagonal tiles only; kv > q -> -inf) ----
            if (k0 + 63 > wrow0) {
                #pragma unroll
                for (int qt = 0; qt < 2; ++qt)
                    #pragma unroll
                    for (int nt = 0; nt < 4; ++nt)
                        #pragma unroll
                        for (int r = 0; r < 4; ++r) {
                            int kvg = k0 + nt*16 + quad*4 + r;
                            int qg  = wrow0 + qt*16 + c;
                            if (kvg > qg) sv[qt][nt][r] = -340.0f;
                        }
            }

            // ---- p = exp2(s); row-sum per lane; pack P^T as B-frags ----
            s16x4 pb[2][4];
            #pragma unroll
            for (int qt = 0; qt < 2; ++qt)
                #pragma unroll
                for (int nt = 0; nt < 4; ++nt) {
                    float p0 = __builtin_amdgcn_exp2f(sv[qt][nt][0]);
                    float p1 = __builtin_amdgcn_exp2f(sv[qt][nt][1]);
                    float p2 = __builtin_amdgcn_exp2f(sv[qt][nt][2]);
                    float p3 = __builtin_amdgcn_exp2f(sv[qt][nt][3]);
                    l_lane[qt] += (p0 + p1) + (p2 + p3);
                    union { uint32_t u[2]; s16x4 v; } pu;
                    pu.u[0] = pk2(p0, p1);
                    pu.u[1] = pk2(p2, p3);
                    pb[qt][nt] = pu.v;
                }

            // ---- O^T += V^T.P^T  (K=16 steps; A=V^T rows from LDS b64) ----
            __builtin_amdgcn_s_setprio(1);
            #pragma unroll
            for (int s4 = 0; s4 < 4; ++s4)
                #pragma unroll
                for (int dt = 0; dt < 4; ++dt) {
                    int row = dt*16 + c;                    // d
                    int chunk = s4*2 + (quad >> 1);
                    int pos = chunk ^ (row & 7);
                    s16x4 vf = *(const s16x4*)(Vs + (size_t)(row*8 + pos)*8 + (quad & 1)*4);
                    o[0][dt] = __builtin_amdgcn_mfma_f32_16x16x16bf16_1k(vf, pb[0][s4], o[0][dt], 0, 0, 0);
                    o[1][dt] = __builtin_amdgcn_mfma_f32_16x16x16bf16_1k(vf, pb[1][s4], o[1][dt], 0, 0, 0);
                }
            __builtin_amdgcn_s_setprio(0);
        }

        int tmp = b0; b0 = b1; b1 = b2; b2 = tmp;     // rotate buffers
    }

    // ---- epilogue: reduce l over quads, scale, store O^T packed ----
    #pragma unroll
    for (int qt = 0; qt < 2; ++qt) {
        float l = l_lane[qt];
        l += __shfl_xor(l, 16);
        l += __shfl_xor(l, 32);
        float inv = 1.0f / l;
        int tok = (int)(q0 + w*32 + qt*16 + c);
        #pragma unroll
        for (int dt = 0; dt < 4; ++dt) {
            ushort4 o4;
            o4.x = f2bf(o[qt][dt][0] * inv);
            o4.y = f2bf(o[qt][dt][1] * inv);
            o4.z = f2bf(o[qt][dt][2] * inv);
            o4.w = f2bf(o[qt][dt][3] * inv);
            *(ushort4*)(O + (tokBase + tok)*DIMD + hcol + dt*16 + quad*4) = o4;
        }
    }
    #undef STAGE_KV
}

// ---------------------------------------------------------------------------
extern "C" void kernel_launch(void* const* d_in, const int* in_sizes, int n_in,
                              void* d_out, int out_size, void* d_ws, size_t ws_size,
                              hipStream_t stream) {
    const float* x  = (const float*)d_in[0];
    // d_in[1] = causal tril mask, deterministic -> handled analytically
    const float* Wq = (const float*)d_in[2];
    const float* Wk = (const float*)d_in[3];
    const float* Wv = (const float*)d_in[4];
    const float* Wo = (const float*)d_in[5];

    uint16_t* ws  = (uint16_t*)d_ws;
    uint16_t* xb  = ws;                      // x bf16 (later reused as attn out)
    uint16_t* wqb = ws + 8388608;            // Wq,Wk,Wv,Wo bf16 contiguous
    uint16_t* wob = wqb + 3*1048576;
    uint16_t* qb  = ws + 12582912;           // Q
    uint16_t* kb  = qb + 8388608;            // K
    uint16_t* vtb = kb + 8388608;            // V transposed per (b,h)
    uint16_t* ab  = xb;                      // attention output reuses xb

    cast_all<<<12288, 256, 0, stream>>>(x, Wq, Wk, Wv, Wo, ws);

    // QKV: 128x384 8-phase counted-vmcnt kernel; 512 blocks = 2 exact rounds.
    gemm_qkv384<<<dim3(64, 8), 512, 0, stream>>>(xb, wqb, qb, vtb);

    attn<<<dim3(64, 16), 256, 0, stream>>>(qb, kb, vtb, ab);

    // Out-projection: 256x128 8-phase kernel; 256 blocks = 1 exact round.
    gemm_out256<<<dim3(32, 8), 512, 0, stream>>>(ab, wob, (float*)d_out);
}

// Round 10
// 241.257 us; speedup vs baseline: 1.5346x; 1.0065x over previous
//
#include <hip/hip_runtime.h>
#include <stdint.h>

#define Bq   4
#define Nseq 2048
#define NH   16
#define HD   64
#define DIMD 1024

typedef float  f32x4   __attribute__((ext_vector_type(4)));
typedef float  f32x16  __attribute__((ext_vector_type(16)));
typedef __bf16 bf16x8  __attribute__((ext_vector_type(8)));
typedef short  s16x4   __attribute__((ext_vector_type(4)));

typedef __attribute__((address_space(1))) void as1_void;
typedef __attribute__((address_space(3))) void as3_void;

static __device__ __forceinline__ uint16_t f2bf(float f) {
    uint32_t u = __builtin_bit_cast(uint32_t, f);
    u += 0x7fffu + ((u >> 16) & 1u);          // RNE
    return (uint16_t)(u >> 16);
}

// truncation-pack two fp32 -> packed bf16x2 (p>=0, 1-ulp bias, cancels in p/l)
static __device__ __forceinline__ uint32_t pk2(float a, float b) {
    uint32_t ua = __builtin_bit_cast(uint32_t, a);
    uint32_t ub = __builtin_bit_cast(uint32_t, b);
    return (ua >> 16) | (ub & 0xffff0000u);
}

static __device__ __forceinline__ void asyncLoad16(const uint16_t* g, uint16_t* l) {
    __builtin_amdgcn_global_load_lds((as1_void*)g, (as3_void*)l, 16, 0, 0);
}

// ---------------------------------------------------------------------------
// cast fp32 -> bf16 : x (8388608) then Wq,Wk,Wv,Wo (4 x 1048576), dst contiguous
// Wq is pre-scaled by SCALE*log2(e) so attention can use exp2 on raw QK dots.
// ---------------------------------------------------------------------------
__global__ void cast_all(const float* __restrict__ x,
                         const float* __restrict__ wq, const float* __restrict__ wk,
                         const float* __restrict__ wv, const float* __restrict__ wo,
                         uint16_t* __restrict__ dst) {
    size_t i = ((size_t)blockIdx.x * blockDim.x + threadIdx.x) * 4;  // elem idx
    const float* src; size_t off; float scale = 1.0f;
    if (i < 8388608) { src = x; off = i; }
    else {
        size_t wI = i - 8388608;
        size_t wi = wI >> 20;
        off = wI & 1048575;
        src = (wi == 0) ? wq : (wi == 1) ? wk : (wi == 2) ? wv : wo;
        if (wi == 0) scale = 0.18033688011112042f;   // (1/sqrt(64)) * log2(e)
    }
    float4 v = *(const float4*)(src + off);
    ushort4 o;
    o.x = f2bf(v.x * scale); o.y = f2bf(v.y * scale);
    o.z = f2bf(v.z * scale); o.w = f2bf(v.w * scale);
    *(ushort4*)(dst + i) = o;
}

#define BARR()  __builtin_amdgcn_s_barrier()
#define SCB0()  __builtin_amdgcn_sched_barrier(0)
#define LGKM()  asm volatile("s_waitcnt lgkmcnt(0)" ::: "memory")
#define PRIO1() __builtin_amdgcn_s_setprio(1)
#define PRIO0() __builtin_amdgcn_s_setprio(0)

// ---------------------------------------------------------------------------
// QKV GEMM: 8-phase counted-vmcnt engine, BM=128 x BN=384 (R7, measured 65.2us,
// conflicts 0). Grid (64,8) = 512 blocks = 2 exact rounds at 1 block/CU.
// Units 8/K-tile (A 2, B 6), 2 staged per phase, vmcnt(4) at P4/P8 only;
// all fragment rows == ln mod 8 -> swizzle conflict-free.
// ---------------------------------------------------------------------------
__global__ __launch_bounds__(512, 2) void gemm_qkv384(
    const uint16_t* __restrict__ A, const uint16_t* __restrict__ W0,
    uint16_t* __restrict__ C0, uint16_t* __restrict__ vtb)
{
    __shared__ __align__(16) uint16_t Asm[2][2][4096];    // [buf][mh][64 rows x 64]
    __shared__ __align__(16) uint16_t Bsm[2][2][12288];   // [buf][nh][3 units x 64 x 64]

    const int t = threadIdx.x, lane = t & 63, w = t >> 6;
    const int wm = w >> 2, wn = w & 3;                    // 2 x 4 wave grid
    const int ln = lane & 15, l4 = lane >> 4;

    const int m0 = blockIdx.x * 128;
    const int n0 = blockIdx.y * 384;                      // global over Q|K|V rows

    const int srow = t >> 3;                              // 0..63
    const int sg   = (t & 7) ^ (srow & 7);
    const uint16_t* aBase = A + (size_t)(m0 + (srow >> 5)*64 + (srow & 31))*DIMD + sg*8;
    const uint16_t* bBase[3];
    #pragma unroll
    for (int j = 0; j < 3; ++j) {
        int f = j*64 + srow;
        int wnf = f / 48, off = f % 48;
        bBase[j] = W0 + (size_t)(n0 + wnf*96 + off)*DIMD + sg*8;
    }

#define SA(mh_, buf_, kk_) asyncLoad16(aBase + (size_t)(mh_)*32*DIMD + (kk_), \
        &Asm[buf_][mh_][t*8])
#define SB(nh_, j_, buf_, kk_) asyncLoad16(bBase[j_] + (size_t)(nh_)*48*DIMD + (kk_), \
        &Bsm[buf_][nh_][(j_)*4096 + t*8])

    SA(0,0,0); SA(1,0,0);
    SB(0,0,0,0); SB(0,1,0,0); SB(0,2,0,0);
    SB(1,0,0,0); SB(1,1,0,0); SB(1,2,0,0);
    SA(0,1,64);
    SB(0,0,1,64); SB(0,1,1,64); SB(0,2,1,64);
    asm volatile("s_waitcnt vmcnt(4)" ::: "memory");
    BARR();

    const int cs0 = ( l4      ^ (ln & 7)) * 8;
    const int cs1 = ((4 + l4) ^ (ln & 7)) * 8;
    const int awo = wm*2048 + ln*64;
    const int bwo = wn*3072 + ln*64;

    bf16x8 af[2][2], bf0[3][2], bf1[3][2];
    f32x4 acc[4][6] = {};

#define LDA(mh_, buf_)                                                         \
    _Pragma("unroll")                                                          \
    for (int mf = 0; mf < 2; ++mf) {                                           \
        af[mf][0] = *(const bf16x8*)(&Asm[buf_][mh_][awo + mf*1024 + cs0]);    \
        af[mf][1] = *(const bf16x8*)(&Asm[buf_][mh_][awo + mf*1024 + cs1]);    \
    }
#define LDB(nh_, buf_, BF)                                                     \
    _Pragma("unroll")                                                          \
    for (int nf = 0; nf < 3; ++nf) {                                           \
        BF[nf][0] = *(const bf16x8*)(&Bsm[buf_][nh_][bwo + nf*1024 + cs0]);    \
        BF[nf][1] = *(const bf16x8*)(&Bsm[buf_][nh_][bwo + nf*1024 + cs1]);    \
    }
#define MFMA12(mh_, nh_, BF)                                                   \
    _Pragma("unroll")                                                          \
    for (int mf = 0; mf < 2; ++mf)                                             \
        _Pragma("unroll")                                                      \
        for (int nf = 0; nf < 3; ++nf) {                                       \
            acc[(mh_)*2+mf][(nh_)*3+nf] = __builtin_amdgcn_mfma_f32_16x16x32_bf16( \
                af[mf][0], BF[nf][0], acc[(mh_)*2+mf][(nh_)*3+nf], 0,0,0);     \
            acc[(mh_)*2+mf][(nh_)*3+nf] = __builtin_amdgcn_mfma_f32_16x16x32_bf16( \
                af[mf][1], BF[nf][1], acc[(mh_)*2+mf][(nh_)*3+nf], 0,0,0);     \
        }

    #pragma unroll 1
    for (int i = 0; i < 8; ++i) {
        const int kk1 = i*128 + 64, kk2 = i*128 + 128, kk3 = i*128 + 192;
        const bool pf = (i < 7);

        LDA(0,0); LDB(0,0,bf0);
        SA(1,1,kk1); SB(1,0,1,kk1);
        BARR(); LGKM(); SCB0();
        PRIO1(); MFMA12(0,0,bf0); PRIO0();
        SCB0(); BARR();

        LDB(1,0,bf1);
        SB(1,1,1,kk1); SB(1,2,1,kk1);
        BARR(); LGKM(); SCB0();
        PRIO1(); MFMA12(0,1,bf1); PRIO0();
        SCB0(); BARR();

        LDA(1,0);
        if (pf) { SA(0,0,kk2); SB(0,0,0,kk2); }
        BARR(); LGKM(); SCB0();
        PRIO1(); MFMA12(1,0,bf0); PRIO0();
        SCB0(); BARR();

        if (pf) { SB(0,1,0,kk2); SB(0,2,0,kk2); }
        BARR(); SCB0();
        PRIO1(); MFMA12(1,1,bf1); PRIO0();
        SCB0();
        if (pf) { asm volatile("s_waitcnt vmcnt(4)" ::: "memory"); }
        else    { asm volatile("s_waitcnt vmcnt(0)" ::: "memory"); }
        BARR();

        LDA(0,1); LDB(0,1,bf0);
        if (pf) { SA(1,0,kk2); SB(1,0,0,kk2); }
        BARR(); LGKM(); SCB0();
        PRIO1(); MFMA12(0,0,bf0); PRIO0();
        SCB0(); BARR();

        LDB(1,1,bf1);
        if (pf) { SB(1,1,0,kk2); SB(1,2,0,kk2); }
        BARR(); LGKM(); SCB0();
        PRIO1(); MFMA12(0,1,bf1); PRIO0();
        SCB0(); BARR();

        LDA(1,1);
        if (pf) { SA(0,1,kk3); SB(0,0,1,kk3); }
        BARR(); LGKM(); SCB0();
        PRIO1(); MFMA12(1,0,bf0); PRIO0();
        SCB0(); BARR();

        if (pf) { SB(0,1,1,kk3); SB(0,2,1,kk3); }
        BARR(); SCB0();
        PRIO1(); MFMA12(1,1,bf1); PRIO0();
        SCB0();
        if (pf) { asm volatile("s_waitcnt vmcnt(4)" ::: "memory"); BARR(); }
    }

#undef SA
#undef SB
#undef LDA
#undef LDB
#undef MFMA12

    // ---- epilogue: C/D 16x16 layout col = ln, row = l4*4 + r ----
    #pragma unroll
    for (int mh = 0; mh < 2; ++mh)
      #pragma unroll
      for (int mf = 0; mf < 2; ++mf)
        #pragma unroll
        for (int nh = 0; nh < 2; ++nh)
          #pragma unroll
          for (int nf = 0; nf < 3; ++nf) {
              const f32x4 a4 = acc[mh*2+mf][nh*3+nf];
              int rowg = m0 + wm*64 + mh*32 + mf*16 + l4*4;   // token (+r)
              int colg = n0 + wn*96 + nh*48 + nf*16 + ln;     // global out dim
              if (colg < 2048) {                               // Q or K, row-major
                  uint16_t* C = C0 + (size_t)(colg >> 10) * 8388608;
                  int col = colg & 1023;
                  #pragma unroll
                  for (int r = 0; r < 4; ++r)
                      C[(size_t)(rowg + r)*1024 + col] = f2bf(a4[r]);
              } else {                                         // V, transposed
                  int dg = colg - 2048;
                  int bb = rowg >> 11, nn = rowg & 2047;
                  ushort4 o4;
                  o4.x = f2bf(a4[0]); o4.y = f2bf(a4[1]);
                  o4.z = f2bf(a4[2]); o4.w = f2bf(a4[3]);
                  *(ushort4*)(vtb + ((size_t)(bb*1024 + dg))*Nseq + nn) = o4;
              }
          }
}

// ---------------------------------------------------------------------------
// Output projection: 8-phase engine, BM=256 x BN=128 -> grid (32,8) = 256
// blocks = exactly one round at 1 block/CU (96 KiB LDS). R9-measured good.
// ---------------------------------------------------------------------------
__global__ __launch_bounds__(512, 2) void gemm_out256(
    const uint16_t* __restrict__ A, const uint16_t* __restrict__ W0,
    float* __restrict__ C)
{
    __shared__ __align__(16) uint16_t Asm[2][2][8192];    // [buf][mh][2 units x 64 x 64]
    __shared__ __align__(16) uint16_t Bsm[2][2][4096];    // [buf][nh][64 rows x 64]

    const int t = threadIdx.x, lane = t & 63, w = t >> 6;
    const int wm = w >> 2, wn = w & 3;                    // 2 x 4 wave grid
    const int ln = lane & 15, l4 = lane >> 4;

    const int m0 = blockIdx.x * 256;
    const int n0 = blockIdx.y * 128;

    const int srow = t >> 3;                              // 0..63
    const int sg   = (t & 7) ^ (srow & 7);
    const uint16_t* aBase = A + (size_t)(m0 + srow)*DIMD + sg*8;
    const uint16_t* bBase = W0 + (size_t)(n0 + (srow >> 4)*32 + (srow & 15))*DIMD + sg*8;

#define SA(mh_, j_, buf_, kk_) asyncLoad16(aBase + (size_t)((j_)*128 + (mh_)*64)*DIMD + (kk_), \
        &Asm[buf_][mh_][(j_)*4096 + t*8])
#define SB(nh_, buf_, kk_) asyncLoad16(bBase + (size_t)(nh_)*16*DIMD + (kk_), \
        &Bsm[buf_][nh_][t*8])

    // prologue: tile0 = B(0), A-mh0(0), A-mh1(0); then B(1), A-mh0(1)
    SB(0,0,0); SB(1,0,0);
    SA(0,0,0,0); SA(0,1,0,0);
    SA(1,0,0,0); SA(1,1,0,0);
    SB(0,1,64); SB(1,1,64);
    SA(0,0,1,64); SA(0,1,1,64);
    asm volatile("s_waitcnt vmcnt(4)" ::: "memory");
    BARR();

    const int cs0 = ( l4      ^ (ln & 7)) * 8;
    const int cs1 = ((4 + l4) ^ (ln & 7)) * 8;
    const int awo = wm*4096 + ln*64;                      // + mf*1024 + cs
    const int bwo = wn*1024 + ln*64;                      // + cs

    bf16x8 af[4][2], bfA[2], bfB[2];
    f32x4 acc[8][2] = {};

#define LDA(mh_, buf_)                                                         \
    _Pragma("unroll")                                                          \
    for (int mf = 0; mf < 4; ++mf) {                                           \
        af[mf][0] = *(const bf16x8*)(&Asm[buf_][mh_][awo + mf*1024 + cs0]);    \
        af[mf][1] = *(const bf16x8*)(&Asm[buf_][mh_][awo + mf*1024 + cs1]);    \
    }
#define LDB(nh_, buf_, BF)                                                     \
    BF[0] = *(const bf16x8*)(&Bsm[buf_][nh_][bwo + cs0]);                      \
    BF[1] = *(const bf16x8*)(&Bsm[buf_][nh_][bwo + cs1]);
#define MFMA8(mh_, nh_, BF)                                                    \
    _Pragma("unroll")                                                          \
    for (int mf = 0; mf < 4; ++mf) {                                           \
        acc[(mh_)*4+mf][nh_] = __builtin_amdgcn_mfma_f32_16x16x32_bf16(        \
            af[mf][0], BF[0], acc[(mh_)*4+mf][nh_], 0,0,0);                    \
        acc[(mh_)*4+mf][nh_] = __builtin_amdgcn_mfma_f32_16x16x32_bf16(        \
            af[mf][1], BF[1], acc[(mh_)*4+mf][nh_], 0,0,0);                    \
    }

    #pragma unroll 1
    for (int i = 0; i < 8; ++i) {                         // tiles 2i (b0), 2i+1 (b1)
        const int kk1 = i*128 + 64, kk2 = i*128 + 128, kk3 = i*128 + 192;
        const bool pf2 = (i < 7);                         // tile 2i+2 exists
        const bool pf3 = (i < 7);                         // tile 2i+3 exists

        // -------- P1: b0 (mh0,nh0); stage A-mh1(2i+1)->b1 --------
        LDA(0,0); LDB(0,0,bfA);
        SA(1,0,1,kk1); SA(1,1,1,kk1);
        BARR(); LGKM(); SCB0();
        PRIO1(); MFMA8(0,0,bfA); PRIO0();
        SCB0(); BARR();

        // -------- P2: b0 (mh0,nh1) --------
        LDB(1,0,bfB);
        BARR(); LGKM(); SCB0();
        PRIO1(); MFMA8(0,1,bfB); PRIO0();
        SCB0(); BARR();

        // -------- P3: b0 (mh1,nh0); stage B(2i+2), A-mh0(2i+2)->b0 --------
        LDA(1,0);
        if (pf2) { SB(0,0,kk2); SB(1,0,kk2); SA(0,0,0,kk2); SA(0,1,0,kk2); }
        BARR(); LGKM(); SCB0();
        PRIO1(); MFMA8(1,0,bfA); PRIO0();
        SCB0(); BARR();

        // -------- P4: b0 (mh1,nh1); vmcnt forces tile 2i+1 --------
        BARR(); SCB0();
        PRIO1(); MFMA8(1,1,bfB); PRIO0();
        SCB0();
        if (pf2) { asm volatile("s_waitcnt vmcnt(4)" ::: "memory"); }
        else     { asm volatile("s_waitcnt vmcnt(0)" ::: "memory"); }
        BARR();

        // -------- P5: b1 (mh0,nh0); stage A-mh1(2i+2)->b0 --------
        LDA(0,1); LDB(0,1,bfA);
        if (pf2) { SA(1,0,0,kk2); SA(1,1,0,kk2); }
        BARR(); LGKM(); SCB0();
        PRIO1(); MFMA8(0,0,bfA); PRIO0();
        SCB0(); BARR();

        // -------- P6: b1 (mh0,nh1) --------
        LDB(1,1,bfB);
        BARR(); LGKM(); SCB0();
        PRIO1(); MFMA8(0,1,bfB); PRIO0();
        SCB0(); BARR();

        // -------- P7: b1 (mh1,nh0); stage B(2i+3), A-mh0(2i+3)->b1 --------
        LDA(1,1);
        if (pf3) { SB(0,1,kk3); SB(1,1,kk3); SA(0,0,1,kk3); SA(0,1,1,kk3); }
        BARR(); LGKM(); SCB0();
        PRIO1(); MFMA8(1,0,bfA); PRIO0();
        SCB0(); BARR();

        // -------- P8: b1 (mh1,nh1); vmcnt forces tile 2i+2 --------
        BARR(); SCB0();
        PRIO1(); MFMA8(1,1,bfB); PRIO0();
        SCB0();
        if (pf3) { asm volatile("s_waitcnt vmcnt(4)" ::: "memory"); BARR(); }
    }

#undef SA
#undef SB
#undef LDA
#undef LDB
#undef MFMA8

    // ---- epilogue: C/D 16x16 layout col = ln, row = l4*4 + r; fp32 out ----
    #pragma unroll
    for (int mh = 0; mh < 2; ++mh)
      #pragma unroll
      for (int mf = 0; mf < 4; ++mf)
        #pragma unroll
        for (int nh = 0; nh < 2; ++nh) {
            const f32x4 a4 = acc[mh*4+mf][nh];
            int rowg = m0 + wm*128 + mh*64 + mf*16 + l4*4;
            int colg = n0 + wn*32 + nh*16 + ln;
            #pragma unroll
            for (int r = 0; r < 4; ++r)
                C[(size_t)(rowg + r)*1024 + colg] = a4[r];
        }
}

// ---------------------------------------------------------------------------
// Flash attention, causal, no-max online softmax, S^T formulation.
// R10 change: T15 att[2] double-pipeline (measured +8-11% on m214 attn).
//   R3 counters (Mfma 15 / VALU 32 / HBM 4 / conflicts 0) = latency-bound on
//   the serial per-tile chain QK -> softmax -> PV. Now QK+softmax of tile t+1
//   (MFMA+VALU) runs in the SAME iteration as PV of tile t (MFMA) -- the two
//   are independent, so the iteration body shrinks to ~max(QK+SM, PV).
// Structure: peel QK(0); per iter: {vmcnt(0)+barrier -> stage(kt+2) ->
// QK/SM(kt+1)->pb_next -> PV(kt)<-pb_cur}. Two NAMED pb sets (pbA/pbB,
// rule #20: no runtime indexing), loop unrolled x2 (end = 2qi+2 is even).
// Hazards: QK(kt+1) reads buf b1 (staged iter kt-1, forced by top barrier);
// stage(kt+2)->b2 whose last reader PV(kt-1) is ordered by the same barrier;
// rotation (b0,b1,b2) = (kt,kt+1,kt+2)%3 verified by induction incl. qi=0.
// vmcnt(0)/iter replaces counted vmcnt (R4 measured that delta ~ +1us).
// Per-wave lastw gates QK/PV without touching barrier uniformity.
// LDS 48 KB -> 3 blocks/CU; launch_bounds(256,3).
// ---------------------------------------------------------------------------
__global__ __launch_bounds__(256, 3) void attn(
    const uint16_t* __restrict__ Q, const uint16_t* __restrict__ K,
    const uint16_t* __restrict__ Vt, uint16_t* __restrict__ O)
{
    __shared__ __align__(16) uint16_t Kb[3][64*64];   // 24 KB (first 16 KB = Q scratch)
    __shared__ __align__(16) uint16_t Vb[3][64*64];   // 24 KB (V^T tiles, rows=d)

    const int t = threadIdx.x, lane = t & 63, w = t >> 6;
    const int quad = lane >> 4, c = lane & 15;
    const int y = blockIdx.y;
    const int qi = (y < 4) ? (15 - y) : (y < 8) ? (y + 4) : (y < 12) ? (y - 4) : (15 - y);
    const int q0 = qi * 128;
    const int bh = blockIdx.x, b = bh >> 4, h = bh & 15;
    const size_t tokBase = (size_t)b * Nseq;
    const int hcol = h * HD;
    uint16_t* Qs = (uint16_t*)Kb;                    // 16 KB scratch (Kb[0..1])

    #define STAGE_KV(k0_, buf_)                                             \
        _Pragma("unroll")                                                    \
        for (int i = 0; i < 2; ++i) {                                        \
            int s = t + 256*i;                                               \
            int row = s >> 3, gg = (s & 7) ^ (row & 7);                      \
            asyncLoad16(K + (tokBase + (k0_) + row)*DIMD + hcol + gg*8,      \
                        Kb[buf_] + (size_t)(w*64 + 256*i)*8);                \
            asyncLoad16(Vt + ((size_t)bh*HD + row)*Nseq + (k0_) + gg*8,      \
                        Vb[buf_] + (size_t)(w*64 + 256*i)*8);                \
        }

    // ---- stage Q (128x64) through scratch, grab fragments, then free it ----
    #pragma unroll
    for (int i = 0; i < 4; ++i) {
        int s = t + 256*i;
        int row = s >> 3, gg = (s & 7) ^ (row & 7);
        asyncLoad16(Q + (tokBase + q0 + row)*DIMD + hcol + gg*8,
                    Qs + (size_t)(w*64 + 256*i)*8);
    }
    __syncthreads();                                  // Q landed
    bf16x8 qf[2][2];
    #pragma unroll
    for (int qt = 0; qt < 2; ++qt)
        #pragma unroll
        for (int ks = 0; ks < 2; ++ks) {
            int row = w*32 + qt*16 + c;
            int pos = (ks*4 + quad) ^ (row & 7);
            qf[qt][ks] = *(const bf16x8*)(Qs + (size_t)(row*8 + pos)*8);
        }
    __syncthreads();                                  // all reads done, scratch free

    const int wrow0 = q0 + w*32;
    const int end   = 2*qi + 2;                       // even, >= 2
    const int lastw = (wrow0 + 31) >> 6;              // last tile this wave computes
    STAGE_KV(0, 0);                                   // tiles 0 and 1 in flight
    STAGE_KV(64, 1);

    f32x4  o[2][4] = {};
    float  l_lane[2] = {0.f, 0.f};
    s16x4  pbA[2][4], pbB[2][4];

    // QK^T + causal mask + exp2 + pack for tile j_ into PB (reads Ks_)
    #define QKSM(j_, PB, KSP)                                                  \
    {                                                                          \
        const uint16_t* Ks_ = (KSP);                                           \
        const int k0_ = (j_) * 64;                                             \
        f32x4 sv[2][4] = {};                                                   \
        __builtin_amdgcn_s_setprio(1);                                         \
        _Pragma("unroll")                                                      \
        for (int nt = 0; nt < 4; ++nt)                                         \
            _Pragma("unroll")                                                  \
            for (int ks = 0; ks < 2; ++ks) {                                   \
                int row = nt*16 + c;                                           \
                int pos = (ks*4 + quad) ^ (row & 7);                           \
                bf16x8 kf = *(const bf16x8*)(Ks_ + (size_t)(row*8 + pos)*8);   \
                sv[0][nt] = __builtin_amdgcn_mfma_f32_16x16x32_bf16(kf, qf[0][ks], sv[0][nt], 0,0,0); \
                sv[1][nt] = __builtin_amdgcn_mfma_f32_16x16x32_bf16(kf, qf[1][ks], sv[1][nt], 0,0,0); \
            }                                                                  \
        __builtin_amdgcn_s_setprio(0);                                         \
        if (k0_ + 63 > wrow0) {                                                \
            _Pragma("unroll")                                                  \
            for (int qt = 0; qt < 2; ++qt)                                     \
                _Pragma("unroll")                                              \
                for (int nt = 0; nt < 4; ++nt)                                 \
                    _Pragma("unroll")                                          \
                    for (int r = 0; r < 4; ++r) {                              \
                        int kvg = k0_ + nt*16 + quad*4 + r;                    \
                        int qg  = wrow0 + qt*16 + c;                           \
                        if (kvg > qg) sv[qt][nt][r] = -340.0f;                 \
                    }                                                          \
        }                                                                      \
        _Pragma("unroll")                                                      \
        for (int qt = 0; qt < 2; ++qt)                                         \
            _Pragma("unroll")                                                  \
            for (int nt = 0; nt < 4; ++nt) {                                   \
                float p0 = __builtin_amdgcn_exp2f(sv[qt][nt][0]);              \
                float p1 = __builtin_amdgcn_exp2f(sv[qt][nt][1]);              \
                float p2 = __builtin_amdgcn_exp2f(sv[qt][nt][2]);              \
                float p3 = __builtin_amdgcn_exp2f(sv[qt][nt][3]);              \
                l_lane[qt] += (p0 + p1) + (p2 + p3);                           \
                union { uint32_t u[2]; s16x4 v; } pu;                          \
                pu.u[0] = pk2(p0, p1);                                         \
                pu.u[1] = pk2(p2, p3);                                         \
                PB[qt][nt] = pu.v;                                             \
            }                                                                  \
    }

    // O^T += V^T.P^T for tile kt_ using PB (reads Vs_)
    #define PVOP(PB, VSP)                                                      \
    {                                                                          \
        const uint16_t* Vs_ = (VSP);                                           \
        __builtin_amdgcn_s_setprio(1);                                         \
        _Pragma("unroll")                                                      \
        for (int s4 = 0; s4 < 4; ++s4)                                         \
            _Pragma("unroll")                                                  \
            for (int dt = 0; dt < 4; ++dt) {                                   \
                int row = dt*16 + c;                                           \
                int chunk = s4*2 + (quad >> 1);                                \
                int pos = chunk ^ (row & 7);                                   \
                s16x4 vf = *(const s16x4*)(Vs_ + (size_t)(row*8 + pos)*8 + (quad & 1)*4); \
                o[0][dt] = __builtin_amdgcn_mfma_f32_16x16x16bf16_1k(vf, PB[0][s4], o[0][dt], 0,0,0); \
                o[1][dt] = __builtin_amdgcn_mfma_f32_16x16x16bf16_1k(vf, PB[1][s4], o[1][dt], 0,0,0); \
            }                                                                  \
        __builtin_amdgcn_s_setprio(0);                                         \
    }

    // ---- peel: QK+softmax for tile 0 (tile 0 forced by own vmcnt + barrier) ----
    asm volatile("s_waitcnt vmcnt(4)\n\ts_barrier" ::: "memory");
    QKSM(0, pbA, Kb[0]);

    int b0 = 0, b1 = 1, b2 = 2;
    for (int kt = 0; kt < end; kt += 2) {
        // ---- even iter: QK(kt+1)->pbB ; PV(kt)<-pbA ----
        asm volatile("s_waitcnt vmcnt(0)\n\ts_barrier" ::: "memory");
        if (kt + 2 < end) { STAGE_KV((kt+2)*64, b2); }
        if (kt + 1 <= lastw) { QKSM(kt+1, pbB, Kb[b1]); }
        if (kt     <= lastw) { PVOP(pbA, Vb[b0]); }
        { int tmp = b0; b0 = b1; b1 = b2; b2 = tmp; }

        // ---- odd iter: QK(kt+2)->pbA ; PV(kt+1)<-pbB ----
        asm volatile("s_waitcnt vmcnt(0)\n\ts_barrier" ::: "memory");
        if (kt + 3 < end) { STAGE_KV((kt+3)*64, b2); }
        if (kt + 2 <= lastw) { QKSM(kt+2, pbA, Kb[b1]); }
        if (kt + 1 <= lastw) { PVOP(pbB, Vb[b0]); }
        { int tmp = b0; b0 = b1; b1 = b2; b2 = tmp; }
    }

    // ---- epilogue: reduce l over quads, scale, store O^T packed ----
    #pragma unroll
    for (int qt = 0; qt < 2; ++qt) {
        float l = l_lane[qt];
        l += __shfl_xor(l, 16);
        l += __shfl_xor(l, 32);
        float inv = 1.0f / l;
        int tok = (int)(q0 + w*32 + qt*16 + c);
        #pragma unroll
        for (int dt = 0; dt < 4; ++dt) {
            ushort4 o4;
            o4.x = f2bf(o[qt][dt][0] * inv);
            o4.y = f2bf(o[qt][dt][1] * inv);
            o4.z = f2bf(o[qt][dt][2] * inv);
            o4.w = f2bf(o[qt][dt][3] * inv);
            *(ushort4*)(O + (tokBase + tok)*DIMD + hcol + dt*16 + quad*4) = o4;
        }
    }
    #undef STAGE_KV
    #undef QKSM
    #undef PVOP
}

// ---------------------------------------------------------------------------
extern "C" void kernel_launch(void* const* d_in, const int* in_sizes, int n_in,
                              void* d_out, int out_size, void* d_ws, size_t ws_size,
                              hipStream_t stream) {
    const float* x  = (const float*)d_in[0];
    // d_in[1] = causal tril mask, deterministic -> handled analytically
    const float* Wq = (const float*)d_in[2];
    const float* Wk = (const float*)d_in[3];
    const float* Wv = (const float*)d_in[4];
    const float* Wo = (const float*)d_in[5];

    uint16_t* ws  = (uint16_t*)d_ws;
    uint16_t* xb  = ws;                      // x bf16 (later reused as attn out)
    uint16_t* wqb = ws + 8388608;            // Wq,Wk,Wv,Wo bf16 contiguous
    uint16_t* wob = wqb + 3*1048576;
    uint16_t* qb  = ws + 12582912;           // Q
    uint16_t* kb  = qb + 8388608;            // K
    uint16_t* vtb = kb + 8388608;            // V transposed per (b,h)
    uint16_t* ab  = xb;                      // attention output reuses xb

    cast_all<<<12288, 256, 0, stream>>>(x, Wq, Wk, Wv, Wo, ws);

    // QKV: 128x384 8-phase counted-vmcnt kernel; 512 blocks = 2 exact rounds.
    gemm_qkv384<<<dim3(64, 8), 512, 0, stream>>>(xb, wqb, qb, vtb);

    attn<<<dim3(64, 16), 256, 0, stream>>>(qb, kb, vtb, ab);

    // Out-projection: 256x128 8-phase kernel; 256 blocks = 1 exact round.
    gemm_out256<<<dim3(32, 8), 512, 0, stream>>>(ab, wob, (float*)d_out);
}